// Round 1
// baseline (280.444 us; speedup 1.0000x reference)
//
#include <hip/hip_runtime.h>
#include <hip/hip_bf16.h>

#define DEV static __device__ __forceinline__

typedef __attribute__((ext_vector_type(8))) short bf16x8;
typedef __attribute__((ext_vector_type(4))) short bf16x4;
typedef __attribute__((ext_vector_type(4))) float f32x4;

constexpr int NB = 4;        // batches
constexpr int SS = 2048;     // seq
constexpr int EE = 1024;     // embed
constexpr int DD = 64;       // low-rank d
constexpr int MTOT = NB * SS;  // 8192 rows total

// Q is pre-scaled by 1/sqrt(D) * log2(e) so softmax runs in exp2 domain.
#define QSCALE (0.125f * 1.44269504088896340736f)

DEV short f2bf(float f) {
    union { float f; unsigned u; } v; v.f = f;
    unsigned u = v.u;
    u += 0x7FFFu + ((u >> 16) & 1u);   // RNE
    return (short)(u >> 16);
}

DEV bf16x8 load8(const float* p, float s) {   // p must be 16B aligned
    float4 u = *(const float4*)(p);
    float4 v = *(const float4*)(p + 4);
    bf16x8 r;
    r[0] = f2bf(u.x * s); r[1] = f2bf(u.y * s); r[2] = f2bf(u.z * s); r[3] = f2bf(u.w * s);
    r[4] = f2bf(v.x * s); r[5] = f2bf(v.y * s); r[6] = f2bf(v.z * s); r[7] = f2bf(v.w * s);
    return r;
}

DEV f32x4 mfma16(bf16x8 a, bf16x8 b, f32x4 c) {
    return __builtin_amdgcn_mfma_f32_16x16x32_bf16(a, b, c, 0, 0, 0);
}

// ---------------------------------------------------------------------------
// K1: projections. blockIdx.y==0: Q from x (scaled). blockIdx.y==1: K and VR
// from y (y read once). Output bf16 [8192][64]. grid (128, 2), block 256.
// ---------------------------------------------------------------------------
__global__ __launch_bounds__(256) void k_proj(
    const float* __restrict__ x, const float* __restrict__ y,
    const float* __restrict__ Wq, const float* __restrict__ bq,
    const float* __restrict__ Wk, const float* __restrict__ bk,
    const float* __restrict__ Wv, const float* __restrict__ bv,
    short* __restrict__ Qb, short* __restrict__ Kb, short* __restrict__ VRb)
{
    const int tid = threadIdx.x, wave = tid >> 6, lane = tid & 63;
    const int r = lane & 15, half = lane >> 4;
    const int rb = blockIdx.x * 64 + wave * 16;      // 16 rows per wave
    const bool isQ = (blockIdx.y == 0);
    const float* src = isQ ? x : y;
    const float* wA  = isQ ? Wq : Wk;
    const float  sA  = isQ ? QSCALE : 1.0f;

    f32x4 accA[4] = {};
    f32x4 accB[4] = {};

    const float* arow = src + (size_t)(rb + r) * EE + half * 8;
    bf16x8 a_cur = load8(arow, 1.0f);
    for (int k0 = 0; k0 < EE; k0 += 32) {
        bf16x8 a_nxt = a_cur;
        if (k0 + 32 < EE) a_nxt = load8(arow + k0 + 32, 1.0f);
        #pragma unroll
        for (int n = 0; n < 4; ++n) {
            bf16x8 b = load8(wA + (size_t)(n * 16 + r) * EE + k0 + half * 8, sA);
            accA[n] = mfma16(a_cur, b, accA[n]);
        }
        if (!isQ) {
            #pragma unroll
            for (int n = 0; n < 4; ++n) {
                bf16x8 b = load8(Wv + (size_t)(n * 16 + r) * EE + k0 + half * 8, 1.0f);
                accB[n] = mfma16(a_cur, b, accB[n]);
            }
        }
        a_cur = a_nxt;
    }

    // D-frag: col = lane&15 (= proj dim), row = (lane>>4)*4 + reg (= seq row)
    const int r4 = half * 4;
    short* dstA = isQ ? Qb : Kb;
    const float* biasA = isQ ? bq : bk;
    #pragma unroll
    for (int n = 0; n < 4; ++n) {
        int col = n * 16 + r;
        float bias = biasA[col] * sA;
        #pragma unroll
        for (int ri = 0; ri < 4; ++ri)
            dstA[(size_t)(rb + r4 + ri) * DD + col] = f2bf(accA[n][ri] + bias);
    }
    if (!isQ) {
        #pragma unroll
        for (int n = 0; n < 4; ++n) {
            int col = n * 16 + r;
            float bias = bv[col];
            #pragma unroll
            for (int ri = 0; ri < 4; ++ri)
                VRb[(size_t)(rb + r4 + ri) * DD + col] = f2bf(accB[n][ri] + bias);
        }
    }
}

// ---------------------------------------------------------------------------
// K2: V^T[v][s] = sum_d WvL[v][d]*VR[s][d] + bvL[v], stored bf16 transposed
// per batch: VT + b*E*S + v*S + s_local. grid (E/64, 8192/64), block 256.
// ---------------------------------------------------------------------------
__global__ __launch_bounds__(256) void k_vproj(
    const float* __restrict__ WvL, const float* __restrict__ bvL,
    const short* __restrict__ VRb, short* __restrict__ VT)
{
    const int tid = threadIdx.x, wave = tid >> 6, lane = tid & 63;
    const int r = lane & 15, half = lane >> 4;
    const int vb = blockIdx.x * 64;
    const int sb = blockIdx.y * 64;
    const int batch = sb >> 11, s_l = sb & (SS - 1);

    __shared__ float lds[64][68];

    f32x4 acc[4] = {};
    #pragma unroll
    for (int kk = 0; kk < 2; ++kk) {
        // B-frag: col = s (lane&15), k = d
        bf16x8 b = *(const bf16x8*)(VRb + (size_t)(sb + wave * 16 + r) * DD + kk * 32 + half * 8);
        #pragma unroll
        for (int m = 0; m < 4; ++m) {
            bf16x8 a = load8(WvL + (size_t)(vb + m * 16 + r) * DD + kk * 32 + half * 8, 1.0f);
            acc[m] = mfma16(a, b, acc[m]);
        }
    }
    // D-frag rows = v, cols = s; transpose through LDS for coalesced V^T rows
    const int r4 = half * 4;
    #pragma unroll
    for (int m = 0; m < 4; ++m)
        #pragma unroll
        for (int ri = 0; ri < 4; ++ri)
            lds[m * 16 + r4 + ri][wave * 16 + r] = acc[m][ri];
    __syncthreads();
    int v = tid >> 2, q4 = (tid & 3) * 16;
    float bias = bvL[vb + v];
    short* dst = VT + (size_t)batch * EE * SS + (size_t)(vb + v) * SS + s_l + q4;
    bf16x8 o0, o1;
    #pragma unroll
    for (int j = 0; j < 8; ++j) o0[j] = f2bf(lds[v][q4 + j] + bias);
    #pragma unroll
    for (int j = 0; j < 8; ++j) o1[j] = f2bf(lds[v][q4 + 8 + j] + bias);
    *(bf16x8*)dst = o0;
    *(bf16x8*)(dst + 8) = o1;
}

// ---------------------------------------------------------------------------
// K3: column softmax (over q). Block = 16 k-columns; 4 waves split q into
// 512-row ranges. Pass1: online max/sumexp stats; combine in LDS; Pass2:
// recompute S' and write P[q][k] bf16. grid (S/16, NB), block 256.
// S' is already in exp2 domain (QSCALE folded into Q).
// ---------------------------------------------------------------------------
__global__ __launch_bounds__(256) void k_softmax(
    const short* __restrict__ Qb, const short* __restrict__ Kb,
    short* __restrict__ P)
{
    const int tid = threadIdx.x, wave = tid >> 6, lane = tid & 63;
    const int r = lane & 15, half = lane >> 4;
    const int batch = blockIdx.y;
    const int kb = blockIdx.x * 16;
    const short* Qp = Qb + (size_t)batch * SS * DD;
    const short* Kp = Kb + (size_t)batch * SS * DD;
    short* Pp = P + (size_t)batch * SS * SS;

    __shared__ float smax[4][16], ssum[4][16];
    __shared__ float lds[4][16][20];

    bf16x8 kf0 = *(const bf16x8*)(Kp + (size_t)(kb + r) * DD + half * 8);
    bf16x8 kf1 = *(const bf16x8*)(Kp + (size_t)(kb + r) * DD + 32 + half * 8);

    const int q0 = wave * 512;
    float m = -1e30f, l = 0.f;
    for (int qt = 0; qt < 32; ++qt) {
        int qrow = q0 + qt * 16 + r;
        bf16x8 a0 = *(const bf16x8*)(Qp + (size_t)qrow * DD + half * 8);
        bf16x8 a1 = *(const bf16x8*)(Qp + (size_t)qrow * DD + 32 + half * 8);
        f32x4 acc = {};
        acc = mfma16(a0, kf0, acc);
        acc = mfma16(a1, kf1, acc);
        float tm = fmaxf(fmaxf(acc[0], acc[1]), fmaxf(acc[2], acc[3]));
        tm = fmaxf(tm, __shfl_xor(tm, 16));
        tm = fmaxf(tm, __shfl_xor(tm, 32));
        float mn = fmaxf(m, tm);
        float sp = exp2f(acc[0] - mn) + exp2f(acc[1] - mn)
                 + exp2f(acc[2] - mn) + exp2f(acc[3] - mn);
        sp += __shfl_xor(sp, 16);
        sp += __shfl_xor(sp, 32);
        l = l * exp2f(m - mn) + sp;
        m = mn;
    }
    if (lane < 16) { smax[wave][lane] = m; ssum[wave][lane] = l; }
    __syncthreads();
    float M = fmaxf(fmaxf(smax[0][r], smax[1][r]), fmaxf(smax[2][r], smax[3][r]));
    float L = ssum[0][r] * exp2f(smax[0][r] - M) + ssum[1][r] * exp2f(smax[1][r] - M)
            + ssum[2][r] * exp2f(smax[2][r] - M) + ssum[3][r] * exp2f(smax[3][r] - M);
    float rl = 1.0f / L;

    for (int qt = 0; qt < 32; ++qt) {
        int qrow = q0 + qt * 16 + r;
        bf16x8 a0 = *(const bf16x8*)(Qp + (size_t)qrow * DD + half * 8);
        bf16x8 a1 = *(const bf16x8*)(Qp + (size_t)qrow * DD + 32 + half * 8);
        f32x4 acc = {};
        acc = mfma16(a0, kf0, acc);
        acc = mfma16(a1, kf1, acc);
        #pragma unroll
        for (int ri = 0; ri < 4; ++ri)
            lds[wave][half * 4 + ri][r] = exp2f(acc[ri] - M) * rl;
        __syncthreads();
        {
            int q = lane >> 2, c4 = (lane & 3) * 4;
            int qg = q0 + qt * 16 + q;
            bf16x4 o;
            #pragma unroll
            for (int j = 0; j < 4; ++j) o[j] = f2bf(lds[wave][q][c4 + j]);
            *(bf16x4*)(Pp + (size_t)qg * SS + kb + c4) = o;
        }
        __syncthreads();
    }
}

// ---------------------------------------------------------------------------
// K4: out[q][v] = sum_k P[q][k] * VT[v][k]. 128x128 block tile, 4 waves of
// 64x64, register double-buffered direct-global frags (both operands
// contiguous along k). grid (E/128, S/128, NB), block 256.
// ---------------------------------------------------------------------------
__global__ __launch_bounds__(256) void k_pv(
    const short* __restrict__ P, const short* __restrict__ VT,
    float* __restrict__ out)
{
    const int tid = threadIdx.x, wave = tid >> 6, lane = tid & 63;
    const int r = lane & 15, half = lane >> 4;
    const int wm = wave >> 1, wn = wave & 1;
    const int batch = blockIdx.z;
    const int qb = blockIdx.y * 128 + wm * 64;
    const int vb = blockIdx.x * 128 + wn * 64;
    const short* Pp = P + (size_t)batch * SS * SS;
    const short* Vp = VT + (size_t)batch * EE * SS;

    const short* ap[4];
    const short* bp[4];
    #pragma unroll
    for (int i = 0; i < 4; ++i) {
        ap[i] = Pp + (size_t)(qb + i * 16 + r) * SS + half * 8;
        bp[i] = Vp + (size_t)(vb + i * 16 + r) * SS + half * 8;
    }

    f32x4 acc[4][4] = {};
    bf16x8 a0[4], b0[4], a1[4], b1[4];
    #pragma unroll
    for (int i = 0; i < 4; ++i) { a0[i] = *(const bf16x8*)(ap[i]); b0[i] = *(const bf16x8*)(bp[i]); }

    for (int k0 = 0; k0 < SS; k0 += 64) {
        #pragma unroll
        for (int i = 0; i < 4; ++i) {
            a1[i] = *(const bf16x8*)(ap[i] + k0 + 32);
            b1[i] = *(const bf16x8*)(bp[i] + k0 + 32);
        }
        #pragma unroll
        for (int mi = 0; mi < 4; ++mi)
            #pragma unroll
            for (int ni = 0; ni < 4; ++ni)
                acc[mi][ni] = mfma16(a0[mi], b0[ni], acc[mi][ni]);
        if (k0 + 64 < SS) {
            #pragma unroll
            for (int i = 0; i < 4; ++i) {
                a0[i] = *(const bf16x8*)(ap[i] + k0 + 64);
                b0[i] = *(const bf16x8*)(bp[i] + k0 + 64);
            }
        }
        #pragma unroll
        for (int mi = 0; mi < 4; ++mi)
            #pragma unroll
            for (int ni = 0; ni < 4; ++ni)
                acc[mi][ni] = mfma16(a1[mi], b1[ni], acc[mi][ni]);
    }

    float* op = out + (size_t)batch * SS * EE;
    const int r4 = half * 4;
    #pragma unroll
    for (int mi = 0; mi < 4; ++mi)
        #pragma unroll
        for (int ni = 0; ni < 4; ++ni)
            #pragma unroll
            for (int ri = 0; ri < 4; ++ri)
                op[(size_t)(qb + mi * 16 + r4 + ri) * EE + vb + ni * 16 + r] = acc[mi][ni][ri];
}

// ---------------------------------------------------------------------------
extern "C" void kernel_launch(void* const* d_in, const int* in_sizes, int n_in,
                              void* d_out, int out_size, void* d_ws, size_t ws_size,
                              hipStream_t stream) {
    (void)in_sizes; (void)n_in; (void)out_size; (void)ws_size;
    const float* x   = (const float*)d_in[0];
    const float* y   = (const float*)d_in[1];
    const float* Wq  = (const float*)d_in[2];
    const float* bq  = (const float*)d_in[3];
    const float* Wk  = (const float*)d_in[4];
    const float* bk  = (const float*)d_in[5];
    const float* WvR = (const float*)d_in[6];
    const float* bvR = (const float*)d_in[7];
    const float* WvL = (const float*)d_in[8];
    const float* bvL = (const float*)d_in[9];
    float* out = (float*)d_out;

    // workspace layout (bf16 shorts): Q, K, VR [8192][64]; VT [4][1024][2048];
    // P [4][2048][2048]  -> total 51 MB
    short* Qb  = (short*)d_ws;
    short* Kb  = Qb  + (size_t)MTOT * DD;
    short* VRb = Kb  + (size_t)MTOT * DD;
    short* VT  = VRb + (size_t)MTOT * DD;
    short* Pb  = VT  + (size_t)NB * EE * SS;

    k_proj<<<dim3(MTOT / 64, 2), 256, 0, stream>>>(x, y, Wq, bq, Wk, bk, WvR, bvR, Qb, Kb, VRb);
    k_vproj<<<dim3(EE / 64, MTOT / 64), 256, 0, stream>>>(WvL, bvL, VRb, VT);
    k_softmax<<<dim3(SS / 16, NB), 256, 0, stream>>>(Qb, Kb, Pb);
    k_pv<<<dim3(EE / 128, SS / 128, NB), 256, 0, stream>>>(Pb, VT, out);
}

// Round 2
// 198.195 us; speedup vs baseline: 1.4150x; 1.4150x over previous
//
#include <hip/hip_runtime.h>
#include <hip/hip_bf16.h>

#define DEV static __device__ __forceinline__
#define AS1 __attribute__((address_space(1)))
#define AS3 __attribute__((address_space(3)))

typedef __attribute__((ext_vector_type(8))) short bf16x8;
typedef __attribute__((ext_vector_type(4))) short bf16x4;
typedef __attribute__((ext_vector_type(4))) float f32x4;

constexpr int NB = 4;        // batches
constexpr int SS = 2048;     // seq
constexpr int EE = 1024;     // embed
constexpr int DD = 64;       // low-rank d
constexpr int MTOT = NB * SS;  // 8192 rows total

// Q is pre-scaled by 1/sqrt(D) * log2(e) so softmax runs in exp2 domain.
#define QSCALE (0.125f * 1.44269504088896340736f)

DEV short f2bf(float f) {
    union { float f; unsigned u; } v; v.f = f;
    unsigned u = v.u;
    u += 0x7FFFu + ((u >> 16) & 1u);   // RNE
    return (short)(u >> 16);
}

DEV bf16x8 load8(const float* p, float s) {   // p must be 16B aligned
    float4 u = *(const float4*)(p);
    float4 v = *(const float4*)(p + 4);
    bf16x8 r;
    r[0] = f2bf(u.x * s); r[1] = f2bf(u.y * s); r[2] = f2bf(u.z * s); r[3] = f2bf(u.w * s);
    r[4] = f2bf(v.x * s); r[5] = f2bf(v.y * s); r[6] = f2bf(v.z * s); r[7] = f2bf(v.w * s);
    return r;
}

DEV f32x4 mfma16(bf16x8 a, bf16x8 b, f32x4 c) {
    return __builtin_amdgcn_mfma_f32_16x16x32_bf16(a, b, c, 0, 0, 0);
}

// ---------------------------------------------------------------------------
// K1: projections. blockIdx.y==0: Q from x (scaled). blockIdx.y==1: K and VR
// from y (y read once). Output bf16 [8192][64]. grid (128, 2), block 256.
// ---------------------------------------------------------------------------
__global__ __launch_bounds__(256) void k_proj(
    const float* __restrict__ x, const float* __restrict__ y,
    const float* __restrict__ Wq, const float* __restrict__ bq,
    const float* __restrict__ Wk, const float* __restrict__ bk,
    const float* __restrict__ Wv, const float* __restrict__ bv,
    short* __restrict__ Qb, short* __restrict__ Kb, short* __restrict__ VRb)
{
    const int tid = threadIdx.x, wave = tid >> 6, lane = tid & 63;
    const int r = lane & 15, half = lane >> 4;
    const int rb = blockIdx.x * 64 + wave * 16;      // 16 rows per wave
    const bool isQ = (blockIdx.y == 0);
    const float* src = isQ ? x : y;
    const float* wA  = isQ ? Wq : Wk;
    const float  sA  = isQ ? QSCALE : 1.0f;

    f32x4 accA[4] = {};
    f32x4 accB[4] = {};

    const float* arow = src + (size_t)(rb + r) * EE + half * 8;
    bf16x8 a_cur = load8(arow, 1.0f);
    for (int k0 = 0; k0 < EE; k0 += 32) {
        bf16x8 a_nxt = a_cur;
        if (k0 + 32 < EE) a_nxt = load8(arow + k0 + 32, 1.0f);
        #pragma unroll
        for (int n = 0; n < 4; ++n) {
            bf16x8 b = load8(wA + (size_t)(n * 16 + r) * EE + k0 + half * 8, sA);
            accA[n] = mfma16(a_cur, b, accA[n]);
        }
        if (!isQ) {
            #pragma unroll
            for (int n = 0; n < 4; ++n) {
                bf16x8 b = load8(Wv + (size_t)(n * 16 + r) * EE + k0 + half * 8, 1.0f);
                accB[n] = mfma16(a_cur, b, accB[n]);
            }
        }
        a_cur = a_nxt;
    }

    // D-frag: col = lane&15 (= proj dim), row = (lane>>4)*4 + reg (= seq row)
    const int r4 = half * 4;
    short* dstA = isQ ? Qb : Kb;
    const float* biasA = isQ ? bq : bk;
    #pragma unroll
    for (int n = 0; n < 4; ++n) {
        int col = n * 16 + r;
        float bias = biasA[col] * sA;
        #pragma unroll
        for (int ri = 0; ri < 4; ++ri)
            dstA[(size_t)(rb + r4 + ri) * DD + col] = f2bf(accA[n][ri] + bias);
    }
    if (!isQ) {
        #pragma unroll
        for (int n = 0; n < 4; ++n) {
            int col = n * 16 + r;
            float bias = bv[col];
            #pragma unroll
            for (int ri = 0; ri < 4; ++ri)
                VRb[(size_t)(rb + r4 + ri) * DD + col] = f2bf(accB[n][ri] + bias);
        }
    }
}

// ---------------------------------------------------------------------------
// K2: V^T[v][s] = sum_d WvL[v][d]*VR[s][d] + bvL[v], stored bf16 transposed
// per batch: VT + b*E*S + v*S + s_local. grid (E/64, 8192/64), block 256.
// ---------------------------------------------------------------------------
__global__ __launch_bounds__(256) void k_vproj(
    const float* __restrict__ WvL, const float* __restrict__ bvL,
    const short* __restrict__ VRb, short* __restrict__ VT)
{
    const int tid = threadIdx.x, wave = tid >> 6, lane = tid & 63;
    const int r = lane & 15, half = lane >> 4;
    const int vb = blockIdx.x * 64;
    const int sb = blockIdx.y * 64;
    const int batch = sb >> 11, s_l = sb & (SS - 1);

    __shared__ float lds[64][68];

    f32x4 acc[4] = {};
    #pragma unroll
    for (int kk = 0; kk < 2; ++kk) {
        // B-frag: col = s (lane&15), k = d
        bf16x8 b = *(const bf16x8*)(VRb + (size_t)(sb + wave * 16 + r) * DD + kk * 32 + half * 8);
        #pragma unroll
        for (int m = 0; m < 4; ++m) {
            bf16x8 a = load8(WvL + (size_t)(vb + m * 16 + r) * DD + kk * 32 + half * 8, 1.0f);
            acc[m] = mfma16(a, b, acc[m]);
        }
    }
    // D-frag rows = v, cols = s; transpose through LDS for coalesced V^T rows
    const int r4 = half * 4;
    #pragma unroll
    for (int m = 0; m < 4; ++m)
        #pragma unroll
        for (int ri = 0; ri < 4; ++ri)
            lds[m * 16 + r4 + ri][wave * 16 + r] = acc[m][ri];
    __syncthreads();
    int v = tid >> 2, q4 = (tid & 3) * 16;
    float bias = bvL[vb + v];
    short* dst = VT + (size_t)batch * EE * SS + (size_t)(vb + v) * SS + s_l + q4;
    bf16x8 o0, o1;
    #pragma unroll
    for (int j = 0; j < 8; ++j) o0[j] = f2bf(lds[v][q4 + j] + bias);
    #pragma unroll
    for (int j = 0; j < 8; ++j) o1[j] = f2bf(lds[v][q4 + 8 + j] + bias);
    *(bf16x8*)dst = o0;
    *(bf16x8*)(dst + 8) = o1;
}

// ---------------------------------------------------------------------------
// K3: column softmax (over q). Block = 16 k-columns; 8 waves split q into
// 256-row ranges, unroll-2 independent MFMA chains. Pass1: online max/sumexp;
// LDS combine; Pass2: recompute S', write P[q][k] bf16 via wave-private LDS
// transpose (no __syncthreads in the loop). grid (S/16, NB), block 512.
// ---------------------------------------------------------------------------
__global__ __launch_bounds__(512) void k_softmax(
    const short* __restrict__ Qb, const short* __restrict__ Kb,
    short* __restrict__ P)
{
    const int tid = threadIdx.x, wave = tid >> 6, lane = tid & 63;
    const int r = lane & 15, half = lane >> 4;
    const int batch = blockIdx.y;
    const int kb = blockIdx.x * 16;
    const short* Qp = Qb + (size_t)batch * SS * DD;
    const short* Kp = Kb + (size_t)batch * SS * DD;
    short* Pp = P + (size_t)batch * SS * SS;

    __shared__ float smax[8][16], ssum[8][16];
    __shared__ float tr[8][2][16][20];

    bf16x8 kf0 = *(const bf16x8*)(Kp + (size_t)(kb + r) * DD + half * 8);
    bf16x8 kf1 = *(const bf16x8*)(Kp + (size_t)(kb + r) * DD + 32 + half * 8);

    const int q0 = wave * 256;
    float m = -1e30f, l = 0.f;
    for (int qt = 0; qt < 16; qt += 2) {
        int qa = q0 + qt * 16 + r;
        const short* pa = Qp + (size_t)qa * DD;
        bf16x8 a0 = *(const bf16x8*)(pa + half * 8);
        bf16x8 a1 = *(const bf16x8*)(pa + 32 + half * 8);
        bf16x8 a2 = *(const bf16x8*)(pa + 16 * DD + half * 8);
        bf16x8 a3 = *(const bf16x8*)(pa + 16 * DD + 32 + half * 8);
        f32x4 c0 = {}, c1 = {};
        c0 = mfma16(a0, kf0, c0); c1 = mfma16(a2, kf0, c1);
        c0 = mfma16(a1, kf1, c0); c1 = mfma16(a3, kf1, c1);
        float tm = fmaxf(fmaxf(fmaxf(c0[0], c0[1]), fmaxf(c0[2], c0[3])),
                         fmaxf(fmaxf(c1[0], c1[1]), fmaxf(c1[2], c1[3])));
        tm = fmaxf(tm, __shfl_xor(tm, 16));
        tm = fmaxf(tm, __shfl_xor(tm, 32));
        float mn = fmaxf(m, tm);
        float sp = exp2f(c0[0] - mn) + exp2f(c0[1] - mn)
                 + exp2f(c0[2] - mn) + exp2f(c0[3] - mn)
                 + exp2f(c1[0] - mn) + exp2f(c1[1] - mn)
                 + exp2f(c1[2] - mn) + exp2f(c1[3] - mn);
        sp += __shfl_xor(sp, 16);
        sp += __shfl_xor(sp, 32);
        l = l * exp2f(m - mn) + sp;
        m = mn;
    }
    if (lane < 16) { smax[wave][lane] = m; ssum[wave][lane] = l; }
    __syncthreads();
    float M = smax[0][r];
    #pragma unroll
    for (int w = 1; w < 8; ++w) M = fmaxf(M, smax[w][r]);
    float L = 0.f;
    #pragma unroll
    for (int w = 0; w < 8; ++w) L += ssum[w][r] * exp2f(smax[w][r] - M);
    float rl = 1.0f / L;

    const int qo = lane >> 2, c4 = (lane & 3) * 4;
    for (int qt = 0; qt < 16; qt += 2) {
        int qa = q0 + qt * 16 + r;
        const short* pa = Qp + (size_t)qa * DD;
        bf16x8 a0 = *(const bf16x8*)(pa + half * 8);
        bf16x8 a1 = *(const bf16x8*)(pa + 32 + half * 8);
        bf16x8 a2 = *(const bf16x8*)(pa + 16 * DD + half * 8);
        bf16x8 a3 = *(const bf16x8*)(pa + 16 * DD + 32 + half * 8);
        f32x4 c0 = {}, c1 = {};
        c0 = mfma16(a0, kf0, c0); c1 = mfma16(a2, kf0, c1);
        c0 = mfma16(a1, kf1, c0); c1 = mfma16(a3, kf1, c1);
        #pragma unroll
        for (int ri = 0; ri < 4; ++ri) {
            tr[wave][0][half * 4 + ri][r] = exp2f(c0[ri] - M) * rl;
            tr[wave][1][half * 4 + ri][r] = exp2f(c1[ri] - M) * rl;
        }
        asm volatile("s_waitcnt lgkmcnt(0)" ::: "memory");
        bf16x4 o0, o1;
        #pragma unroll
        for (int j = 0; j < 4; ++j) o0[j] = f2bf(tr[wave][0][qo][c4 + j]);
        #pragma unroll
        for (int j = 0; j < 4; ++j) o1[j] = f2bf(tr[wave][1][qo][c4 + j]);
        *(bf16x4*)(Pp + (size_t)(q0 + qt * 16 + qo) * SS + kb + c4) = o0;
        *(bf16x4*)(Pp + (size_t)(q0 + qt * 16 + 16 + qo) * SS + kb + c4) = o1;
        asm volatile("s_waitcnt lgkmcnt(0)" ::: "memory");
    }
}

// ---------------------------------------------------------------------------
// K4: out[q][v] = sum_k P[q][k] * VT[v][k]. m97 structure: 128x128 tile,
// BK=64, global_load_lds(16B) staging into linear LDS with XOR-pre-swizzled
// global source; swizzled ds_read_b128 frag loads (conflict-free). 4 waves
// of 64x64. grid (E/128, S/128, NB), block 256.
// ---------------------------------------------------------------------------
__global__ __launch_bounds__(256) void k_pv(
    const short* __restrict__ P, const short* __restrict__ VT,
    float* __restrict__ out)
{
    const int tid = threadIdx.x, wave = tid >> 6, lane = tid & 63;
    const int r = lane & 15, half = lane >> 4;
    const int wm = wave >> 1, wn = wave & 1;
    const int batch = blockIdx.z;
    const int qB = blockIdx.y * 128;
    const int vB = blockIdx.x * 128;
    const short* Pp = P + (size_t)batch * SS * SS;
    const short* Vp = VT + (size_t)batch * EE * SS;

    __shared__ short As[128 * 64];
    __shared__ short Bs[128 * 64];

    // staging: each wave-inst covers 8 rows (8 lanes/row x 16B). LDS dest is
    // linear; the source chunk is XOR-pre-swizzled so a swizzled ds_read is
    // conflict-free (rule: both-sides-or-neither).
    const int l8 = lane >> 3;
    const int cSrc = ((lane & 7) ^ l8) * 8;          // shorts
    const short* aSrc = Pp + (size_t)(qB + wave * 8 + l8) * SS + cSrc;
    const short* bSrc = Vp + (size_t)(vB + wave * 8 + l8) * SS + cSrc;
    short* aDst = As + wave * 8 * 64;
    short* bDst = Bs + wave * 8 * 64;

    f32x4 acc[4][4] = {};
    const int sw = r & 7;

    for (int k0 = 0; k0 < SS; k0 += 64) {
        #pragma unroll
        for (int i = 0; i < 4; ++i) {
            __builtin_amdgcn_global_load_lds(
                (const AS1 void*)(aSrc + (size_t)i * 32 * SS + k0),
                (AS3 void*)(aDst + i * 32 * 64), 16, 0, 0);
            __builtin_amdgcn_global_load_lds(
                (const AS1 void*)(bSrc + (size_t)i * 32 * SS + k0),
                (AS3 void*)(bDst + i * 32 * 64), 16, 0, 0);
        }
        __syncthreads();
        #pragma unroll
        for (int kk = 0; kk < 2; ++kk) {
            const int co = ((kk * 4 + half) ^ sw) * 8;
            bf16x8 a[4], b[4];
            #pragma unroll
            for (int i = 0; i < 4; ++i) {
                a[i] = *(const bf16x8*)(As + (wm * 64 + i * 16 + r) * 64 + co);
                b[i] = *(const bf16x8*)(Bs + (wn * 64 + i * 16 + r) * 64 + co);
            }
            #pragma unroll
            for (int mi = 0; mi < 4; ++mi)
                #pragma unroll
                for (int ni = 0; ni < 4; ++ni)
                    acc[mi][ni] = mfma16(a[mi], b[ni], acc[mi][ni]);
        }
        __syncthreads();
    }

    float* op = out + (size_t)batch * SS * EE;
    const int r4 = half * 4;
    #pragma unroll
    for (int mi = 0; mi < 4; ++mi)
        #pragma unroll
        for (int ni = 0; ni < 4; ++ni)
            #pragma unroll
            for (int ri = 0; ri < 4; ++ri)
                op[(size_t)(qB + wm * 64 + mi * 16 + r4 + ri) * EE + vB + wn * 64 + ni * 16 + r] = acc[mi][ni][ri];
}

// ---------------------------------------------------------------------------
extern "C" void kernel_launch(void* const* d_in, const int* in_sizes, int n_in,
                              void* d_out, int out_size, void* d_ws, size_t ws_size,
                              hipStream_t stream) {
    (void)in_sizes; (void)n_in; (void)out_size; (void)ws_size;
    const float* x   = (const float*)d_in[0];
    const float* y   = (const float*)d_in[1];
    const float* Wq  = (const float*)d_in[2];
    const float* bq  = (const float*)d_in[3];
    const float* Wk  = (const float*)d_in[4];
    const float* bk  = (const float*)d_in[5];
    const float* WvR = (const float*)d_in[6];
    const float* bvR = (const float*)d_in[7];
    const float* WvL = (const float*)d_in[8];
    const float* bvL = (const float*)d_in[9];
    float* out = (float*)d_out;

    // workspace layout (bf16 shorts): Q, K, VR [8192][64]; VT [4][1024][2048];
    // P [4][2048][2048]  -> total 51 MB
    short* Qb  = (short*)d_ws;
    short* Kb  = Qb  + (size_t)MTOT * DD;
    short* VRb = Kb  + (size_t)MTOT * DD;
    short* VT  = VRb + (size_t)MTOT * DD;
    short* Pb  = VT  + (size_t)NB * EE * SS;

    k_proj<<<dim3(MTOT / 64, 2), 256, 0, stream>>>(x, y, Wq, bq, Wk, bk, WvR, bvR, Qb, Kb, VRb);
    k_vproj<<<dim3(EE / 64, MTOT / 64), 256, 0, stream>>>(WvL, bvL, VRb, VT);
    k_softmax<<<dim3(SS / 16, NB), 512, 0, stream>>>(Qb, Kb, Pb);
    k_pv<<<dim3(EE / 128, SS / 128, NB), 256, 0, stream>>>(Pb, VT, out);
}

// Round 3
// 140.542 us; speedup vs baseline: 1.9954x; 1.4102x over previous
//
#include <hip/hip_runtime.h>
#include <hip/hip_bf16.h>

#define DEV static __device__ __forceinline__
#define AS1 __attribute__((address_space(1)))
#define AS3 __attribute__((address_space(3)))

typedef __attribute__((ext_vector_type(8))) short bf16x8;
typedef __attribute__((ext_vector_type(4))) short bf16x4;
typedef __attribute__((ext_vector_type(4))) float f32x4;

constexpr int NB = 4;        // batches
constexpr int SS = 2048;     // seq
constexpr int EE = 1024;     // embed
constexpr int DD = 64;       // low-rank d
constexpr int MTOT = NB * SS;  // 8192 rows total

// Q is pre-scaled by 1/sqrt(D) * log2(e) so softmax runs in exp2 domain.
#define QSCALE (0.125f * 1.44269504088896340736f)

DEV short f2bf(float f) {
    union { float f; unsigned u; } v; v.f = f;
    unsigned u = v.u;
    u += 0x7FFFu + ((u >> 16) & 1u);   // RNE
    return (short)(u >> 16);
}

DEV bf16x8 load8(const float* p, float s) {   // p must be 16B aligned
    float4 u = *(const float4*)(p);
    float4 v = *(const float4*)(p + 4);
    bf16x8 r;
    r[0] = f2bf(u.x * s); r[1] = f2bf(u.y * s); r[2] = f2bf(u.z * s); r[3] = f2bf(u.w * s);
    r[4] = f2bf(v.x * s); r[5] = f2bf(v.y * s); r[6] = f2bf(v.z * s); r[7] = f2bf(v.w * s);
    return r;
}

DEV f32x4 mfma16(bf16x8 a, bf16x8 b, f32x4 c) {
    return __builtin_amdgcn_mfma_f32_16x16x32_bf16(a, b, c, 0, 0, 0);
}

// ---------------------------------------------------------------------------
// K0: pre-convert projection weights to bf16 (Wq scaled by QSCALE).
// 65536 elements per matrix; grid 64, block 256, 4 elem/thread/matrix.
// ---------------------------------------------------------------------------
__global__ __launch_bounds__(256) void k_prep(
    const float* __restrict__ Wq, const float* __restrict__ Wk,
    const float* __restrict__ Wv,
    short* __restrict__ Wqb, short* __restrict__ Wkb, short* __restrict__ Wvb)
{
    int idx = (blockIdx.x * 256 + threadIdx.x) * 4;
    float4 q = *(const float4*)(Wq + idx);
    float4 k = *(const float4*)(Wk + idx);
    float4 v = *(const float4*)(Wv + idx);
    bf16x4 oq, ok, ov;
    oq[0] = f2bf(q.x * QSCALE); oq[1] = f2bf(q.y * QSCALE);
    oq[2] = f2bf(q.z * QSCALE); oq[3] = f2bf(q.w * QSCALE);
    ok[0] = f2bf(k.x); ok[1] = f2bf(k.y); ok[2] = f2bf(k.z); ok[3] = f2bf(k.w);
    ov[0] = f2bf(v.x); ov[1] = f2bf(v.y); ov[2] = f2bf(v.z); ov[3] = f2bf(v.w);
    *(bf16x4*)(Wqb + idx) = oq;
    *(bf16x4*)(Wkb + idx) = ok;
    *(bf16x4*)(Wvb + idx) = ov;
}

// ---------------------------------------------------------------------------
// K1: projections, split-K. Block = 16 rows; 4 waves each own a K-quarter
// (256) and accumulate partial frags; LDS reduce at the end. blockIdx.y==0:
// Q from x; ==1: K and VR from y (y read once). grid (512, 2), block 256.
// ---------------------------------------------------------------------------
__global__ __launch_bounds__(256) void k_proj(
    const float* __restrict__ x, const float* __restrict__ y,
    const short* __restrict__ Wqb, const short* __restrict__ Wkb,
    const short* __restrict__ Wvb,
    const float* __restrict__ bq, const float* __restrict__ bk,
    const float* __restrict__ bv,
    short* __restrict__ Qb, short* __restrict__ Kb, short* __restrict__ VRb)
{
    const int tid = threadIdx.x, wave = tid >> 6, lane = tid & 63;
    const int r = lane & 15, half = lane >> 4;
    const int rb = blockIdx.x * 16;
    const bool isQ = (blockIdx.y == 0);
    const float* src = isQ ? x : y;
    const short* wA = isQ ? Wqb : Wkb;
    const int kq = wave * 256;

    __shared__ f32x4 red[4][8][64];

    f32x4 accA[4] = {}, accB[4] = {};
    const float* arow = src + (size_t)(rb + r) * EE + kq + half * 8;
    const short* wrow = wA + kq + half * 8;
    const short* vrow = Wvb + kq + half * 8;

    #pragma unroll
    for (int it = 0; it < 8; ++it) {
        bf16x8 a = load8(arow + it * 32, 1.0f);
        #pragma unroll
        for (int n = 0; n < 4; ++n) {
            bf16x8 b = *(const bf16x8*)(wrow + (size_t)(n * 16 + r) * EE + it * 32);
            accA[n] = mfma16(a, b, accA[n]);
        }
        if (!isQ) {
            #pragma unroll
            for (int n = 0; n < 4; ++n) {
                bf16x8 b = *(const bf16x8*)(vrow + (size_t)(n * 16 + r) * EE + it * 32);
                accB[n] = mfma16(a, b, accB[n]);
            }
        }
    }

    #pragma unroll
    for (int n = 0; n < 4; ++n) red[wave][n][lane] = accA[n];
    if (!isQ) {
        #pragma unroll
        for (int n = 0; n < 4; ++n) red[wave][4 + n][lane] = accB[n];
    }
    __syncthreads();

    // wave w reduces output-col frag n=w (and 4+w for VR)
    const int n = wave;
    const int col = n * 16 + r;
    f32x4 s = red[0][n][lane];
    #pragma unroll
    for (int w = 1; w < 4; ++w) s += red[w][n][lane];
    float biasA = isQ ? (bq[col] * QSCALE) : bk[col];
    short* dstA = isQ ? Qb : Kb;
    #pragma unroll
    for (int ri = 0; ri < 4; ++ri)
        dstA[(size_t)(rb + half * 4 + ri) * DD + col] = f2bf(s[ri] + biasA);
    if (!isQ) {
        f32x4 t = red[0][4 + n][lane];
        #pragma unroll
        for (int w = 1; w < 4; ++w) t += red[w][4 + n][lane];
        float biasB = bv[col];
        #pragma unroll
        for (int ri = 0; ri < 4; ++ri)
            VRb[(size_t)(rb + half * 4 + ri) * DD + col] = f2bf(t[ri] + biasB);
    }
}

// ---------------------------------------------------------------------------
// K2: V^T[v][s] = sum_d WvL[v][d]*VR[s][d] + bvL[v], stored bf16 transposed
// per batch: VT + b*E*S + v*S + s_local. grid (E/64, 8192/64), block 256.
// ---------------------------------------------------------------------------
__global__ __launch_bounds__(256) void k_vproj(
    const float* __restrict__ WvL, const float* __restrict__ bvL,
    const short* __restrict__ VRb, short* __restrict__ VT)
{
    const int tid = threadIdx.x, wave = tid >> 6, lane = tid & 63;
    const int r = lane & 15, half = lane >> 4;
    const int vb = blockIdx.x * 64;
    const int sb = blockIdx.y * 64;
    const int batch = sb >> 11, s_l = sb & (SS - 1);

    __shared__ float lds[64][68];

    f32x4 acc[4] = {};
    #pragma unroll
    for (int kk = 0; kk < 2; ++kk) {
        // B-frag: col = s (lane&15), k = d
        bf16x8 b = *(const bf16x8*)(VRb + (size_t)(sb + wave * 16 + r) * DD + kk * 32 + half * 8);
        #pragma unroll
        for (int m = 0; m < 4; ++m) {
            bf16x8 a = load8(WvL + (size_t)(vb + m * 16 + r) * DD + kk * 32 + half * 8, 1.0f);
            acc[m] = mfma16(a, b, acc[m]);
        }
    }
    // D-frag rows = v, cols = s; transpose through LDS for coalesced V^T rows
    const int r4 = half * 4;
    #pragma unroll
    for (int m = 0; m < 4; ++m)
        #pragma unroll
        for (int ri = 0; ri < 4; ++ri)
            lds[m * 16 + r4 + ri][wave * 16 + r] = acc[m][ri];
    __syncthreads();
    int v = tid >> 2, q4 = (tid & 3) * 16;
    float bias = bvL[vb + v];
    short* dst = VT + (size_t)batch * EE * SS + (size_t)(vb + v) * SS + s_l + q4;
    bf16x8 o0, o1;
    #pragma unroll
    for (int j = 0; j < 8; ++j) o0[j] = f2bf(lds[v][q4 + j] + bias);
    #pragma unroll
    for (int j = 0; j < 8; ++j) o1[j] = f2bf(lds[v][q4 + 8 + j] + bias);
    *(bf16x8*)dst = o0;
    *(bf16x8*)(dst + 8) = o1;
}

// ---------------------------------------------------------------------------
// K3: column softmax (over q). Block = 16 k-columns; 8 waves split q into
// 256-row ranges, unroll-2 independent MFMA chains. Pass1: online max/sumexp;
// LDS combine; Pass2: recompute S', write P[q][k] bf16 via wave-private LDS
// transpose (no __syncthreads in the loop). grid (S/16, NB), block 512.
// ---------------------------------------------------------------------------
__global__ __launch_bounds__(512) void k_softmax(
    const short* __restrict__ Qb, const short* __restrict__ Kb,
    short* __restrict__ P)
{
    const int tid = threadIdx.x, wave = tid >> 6, lane = tid & 63;
    const int r = lane & 15, half = lane >> 4;
    const int batch = blockIdx.y;
    const int kb = blockIdx.x * 16;
    const short* Qp = Qb + (size_t)batch * SS * DD;
    const short* Kp = Kb + (size_t)batch * SS * DD;
    short* Pp = P + (size_t)batch * SS * SS;

    __shared__ float smax[8][16], ssum[8][16];
    __shared__ float tr[8][2][16][20];

    bf16x8 kf0 = *(const bf16x8*)(Kp + (size_t)(kb + r) * DD + half * 8);
    bf16x8 kf1 = *(const bf16x8*)(Kp + (size_t)(kb + r) * DD + 32 + half * 8);

    const int q0 = wave * 256;
    float m = -1e30f, l = 0.f;
    for (int qt = 0; qt < 16; qt += 2) {
        int qa = q0 + qt * 16 + r;
        const short* pa = Qp + (size_t)qa * DD;
        bf16x8 a0 = *(const bf16x8*)(pa + half * 8);
        bf16x8 a1 = *(const bf16x8*)(pa + 32 + half * 8);
        bf16x8 a2 = *(const bf16x8*)(pa + 16 * DD + half * 8);
        bf16x8 a3 = *(const bf16x8*)(pa + 16 * DD + 32 + half * 8);
        f32x4 c0 = {}, c1 = {};
        c0 = mfma16(a0, kf0, c0); c1 = mfma16(a2, kf0, c1);
        c0 = mfma16(a1, kf1, c0); c1 = mfma16(a3, kf1, c1);
        float tm = fmaxf(fmaxf(fmaxf(c0[0], c0[1]), fmaxf(c0[2], c0[3])),
                         fmaxf(fmaxf(c1[0], c1[1]), fmaxf(c1[2], c1[3])));
        tm = fmaxf(tm, __shfl_xor(tm, 16));
        tm = fmaxf(tm, __shfl_xor(tm, 32));
        float mn = fmaxf(m, tm);
        float sp = exp2f(c0[0] - mn) + exp2f(c0[1] - mn)
                 + exp2f(c0[2] - mn) + exp2f(c0[3] - mn)
                 + exp2f(c1[0] - mn) + exp2f(c1[1] - mn)
                 + exp2f(c1[2] - mn) + exp2f(c1[3] - mn);
        sp += __shfl_xor(sp, 16);
        sp += __shfl_xor(sp, 32);
        l = l * exp2f(m - mn) + sp;
        m = mn;
    }
    if (lane < 16) { smax[wave][lane] = m; ssum[wave][lane] = l; }
    __syncthreads();
    float M = smax[0][r];
    #pragma unroll
    for (int w = 1; w < 8; ++w) M = fmaxf(M, smax[w][r]);
    float L = 0.f;
    #pragma unroll
    for (int w = 0; w < 8; ++w) L += ssum[w][r] * exp2f(smax[w][r] - M);
    float rl = 1.0f / L;

    const int qo = lane >> 2, c4 = (lane & 3) * 4;
    for (int qt = 0; qt < 16; qt += 2) {
        int qa = q0 + qt * 16 + r;
        const short* pa = Qp + (size_t)qa * DD;
        bf16x8 a0 = *(const bf16x8*)(pa + half * 8);
        bf16x8 a1 = *(const bf16x8*)(pa + 32 + half * 8);
        bf16x8 a2 = *(const bf16x8*)(pa + 16 * DD + half * 8);
        bf16x8 a3 = *(const bf16x8*)(pa + 16 * DD + 32 + half * 8);
        f32x4 c0 = {}, c1 = {};
        c0 = mfma16(a0, kf0, c0); c1 = mfma16(a2, kf0, c1);
        c0 = mfma16(a1, kf1, c0); c1 = mfma16(a3, kf1, c1);
        #pragma unroll
        for (int ri = 0; ri < 4; ++ri) {
            tr[wave][0][half * 4 + ri][r] = exp2f(c0[ri] - M) * rl;
            tr[wave][1][half * 4 + ri][r] = exp2f(c1[ri] - M) * rl;
        }
        asm volatile("s_waitcnt lgkmcnt(0)" ::: "memory");
        bf16x4 o0, o1;
        #pragma unroll
        for (int j = 0; j < 4; ++j) o0[j] = f2bf(tr[wave][0][qo][c4 + j]);
        #pragma unroll
        for (int j = 0; j < 4; ++j) o1[j] = f2bf(tr[wave][1][qo][c4 + j]);
        *(bf16x4*)(Pp + (size_t)(q0 + qt * 16 + qo) * SS + kb + c4) = o0;
        *(bf16x4*)(Pp + (size_t)(q0 + qt * 16 + 16 + qo) * SS + kb + c4) = o1;
        asm volatile("s_waitcnt lgkmcnt(0)" ::: "memory");
    }
}

// ---------------------------------------------------------------------------
// K4: out[q][v] = sum_k P[q][k] * VT[v][k]. m97 structure: 128x128 tile,
// BK=64, global_load_lds(16B) staging into linear LDS with XOR-pre-swizzled
// global source; swizzled ds_read_b128 frag loads (conflict-free). 4 waves
// of 64x64. grid (E/128, S/128, NB), block 256.
// ---------------------------------------------------------------------------
__global__ __launch_bounds__(256) void k_pv(
    const short* __restrict__ P, const short* __restrict__ VT,
    float* __restrict__ out)
{
    const int tid = threadIdx.x, wave = tid >> 6, lane = tid & 63;
    const int r = lane & 15, half = lane >> 4;
    const int wm = wave >> 1, wn = wave & 1;
    const int batch = blockIdx.z;
    const int qB = blockIdx.y * 128;
    const int vB = blockIdx.x * 128;
    const short* Pp = P + (size_t)batch * SS * SS;
    const short* Vp = VT + (size_t)batch * EE * SS;

    __shared__ short As[128 * 64];
    __shared__ short Bs[128 * 64];

    // staging: each wave-inst covers 8 rows (8 lanes/row x 16B). LDS dest is
    // linear; the source chunk is XOR-pre-swizzled so a swizzled ds_read is
    // conflict-free (rule: both-sides-or-neither).
    const int l8 = lane >> 3;
    const int cSrc = ((lane & 7) ^ l8) * 8;          // shorts
    const short* aSrc = Pp + (size_t)(qB + wave * 8 + l8) * SS + cSrc;
    const short* bSrc = Vp + (size_t)(vB + wave * 8 + l8) * SS + cSrc;
    short* aDst = As + wave * 8 * 64;
    short* bDst = Bs + wave * 8 * 64;

    f32x4 acc[4][4] = {};
    const int sw = r & 7;

    for (int k0 = 0; k0 < SS; k0 += 64) {
        #pragma unroll
        for (int i = 0; i < 4; ++i) {
            __builtin_amdgcn_global_load_lds(
                (const AS1 void*)(aSrc + (size_t)i * 32 * SS + k0),
                (AS3 void*)(aDst + i * 32 * 64), 16, 0, 0);
            __builtin_amdgcn_global_load_lds(
                (const AS1 void*)(bSrc + (size_t)i * 32 * SS + k0),
                (AS3 void*)(bDst + i * 32 * 64), 16, 0, 0);
        }
        __syncthreads();
        #pragma unroll
        for (int kk = 0; kk < 2; ++kk) {
            const int co = ((kk * 4 + half) ^ sw) * 8;
            bf16x8 a[4], b[4];
            #pragma unroll
            for (int i = 0; i < 4; ++i) {
                a[i] = *(const bf16x8*)(As + (wm * 64 + i * 16 + r) * 64 + co);
                b[i] = *(const bf16x8*)(Bs + (wn * 64 + i * 16 + r) * 64 + co);
            }
            #pragma unroll
            for (int mi = 0; mi < 4; ++mi)
                #pragma unroll
                for (int ni = 0; ni < 4; ++ni)
                    acc[mi][ni] = mfma16(a[mi], b[ni], acc[mi][ni]);
        }
        __syncthreads();
    }

    float* op = out + (size_t)batch * SS * EE;
    const int r4 = half * 4;
    #pragma unroll
    for (int mi = 0; mi < 4; ++mi)
        #pragma unroll
        for (int ni = 0; ni < 4; ++ni)
            #pragma unroll
            for (int ri = 0; ri < 4; ++ri)
                op[(size_t)(qB + wm * 64 + mi * 16 + r4 + ri) * EE + vB + wn * 64 + ni * 16 + r] = acc[mi][ni][ri];
}

// ---------------------------------------------------------------------------
extern "C" void kernel_launch(void* const* d_in, const int* in_sizes, int n_in,
                              void* d_out, int out_size, void* d_ws, size_t ws_size,
                              hipStream_t stream) {
    (void)in_sizes; (void)n_in; (void)out_size; (void)ws_size;
    const float* x   = (const float*)d_in[0];
    const float* y   = (const float*)d_in[1];
    const float* Wq  = (const float*)d_in[2];
    const float* bq  = (const float*)d_in[3];
    const float* Wk  = (const float*)d_in[4];
    const float* bk  = (const float*)d_in[5];
    const float* WvR = (const float*)d_in[6];
    const float* bvR = (const float*)d_in[7];
    const float* WvL = (const float*)d_in[8];
    const float* bvL = (const float*)d_in[9];
    float* out = (float*)d_out;

    // workspace layout (bf16 shorts): Q, K, VR [8192][64]; VT [4][1024][2048];
    // P [4][2048][2048]; Wq/Wk/WvR bf16 [64][1024]  -> total ~51.8 MB
    short* Qb  = (short*)d_ws;
    short* Kb  = Qb  + (size_t)MTOT * DD;
    short* VRb = Kb  + (size_t)MTOT * DD;
    short* VT  = VRb + (size_t)MTOT * DD;
    short* Pb  = VT  + (size_t)NB * EE * SS;
    short* Wqb = Pb  + (size_t)NB * SS * SS;
    short* Wkb = Wqb + (size_t)DD * EE;
    short* Wvb = Wkb + (size_t)DD * EE;

    k_prep<<<dim3(DD * EE / 1024), 256, 0, stream>>>(Wq, Wk, WvR, Wqb, Wkb, Wvb);
    k_proj<<<dim3(MTOT / 16, 2), 256, 0, stream>>>(x, y, Wqb, Wkb, Wvb, bq, bk, bvR, Qb, Kb, VRb);
    k_vproj<<<dim3(EE / 64, MTOT / 64), 256, 0, stream>>>(WvL, bvL, VRb, VT);
    k_softmax<<<dim3(SS / 16, NB), 512, 0, stream>>>(Qb, Kb, Pb);
    k_pv<<<dim3(EE / 128, SS / 128, NB), 256, 0, stream>>>(Pb, VT, out);
}

// Round 4
// 138.717 us; speedup vs baseline: 2.0217x; 1.0132x over previous
//
#include <hip/hip_runtime.h>
#include <hip/hip_bf16.h>

#define DEV static __device__ __forceinline__
#define AS1 __attribute__((address_space(1)))
#define AS3 __attribute__((address_space(3)))

typedef __attribute__((ext_vector_type(8))) short bf16x8;
typedef __attribute__((ext_vector_type(4))) short bf16x4;
typedef __attribute__((ext_vector_type(4))) float f32x4;

constexpr int NB = 4;        // batches
constexpr int SS = 2048;     // seq
constexpr int EE = 1024;     // embed
constexpr int DD = 64;       // low-rank d
constexpr int MTOT = NB * SS;  // 8192 rows total

// Q is pre-scaled by 1/sqrt(D) * log2(e) so softmax runs in exp2 domain.
#define QSCALE (0.125f * 1.44269504088896340736f)

DEV short f2bf(float f) {
    union { float f; unsigned u; } v; v.f = f;
    unsigned u = v.u;
    u += 0x7FFFu + ((u >> 16) & 1u);   // RNE
    return (short)(u >> 16);
}

DEV bf16x8 load8(const float* p, float s) {   // p must be 16B aligned
    float4 u = *(const float4*)(p);
    float4 v = *(const float4*)(p + 4);
    bf16x8 r;
    r[0] = f2bf(u.x * s); r[1] = f2bf(u.y * s); r[2] = f2bf(u.z * s); r[3] = f2bf(u.w * s);
    r[4] = f2bf(v.x * s); r[5] = f2bf(v.y * s); r[6] = f2bf(v.z * s); r[7] = f2bf(v.w * s);
    return r;
}

DEV f32x4 mfma16(bf16x8 a, bf16x8 b, f32x4 c) {
    return __builtin_amdgcn_mfma_f32_16x16x32_bf16(a, b, c, 0, 0, 0);
}

// ---------------------------------------------------------------------------
// K0: pre-convert projection weights to bf16 (Wq scaled by QSCALE).
// ---------------------------------------------------------------------------
__global__ __launch_bounds__(256) void k_prep(
    const float* __restrict__ Wq, const float* __restrict__ Wk,
    const float* __restrict__ Wv,
    short* __restrict__ Wqb, short* __restrict__ Wkb, short* __restrict__ Wvb)
{
    int idx = (blockIdx.x * 256 + threadIdx.x) * 4;
    float4 q = *(const float4*)(Wq + idx);
    float4 k = *(const float4*)(Wk + idx);
    float4 v = *(const float4*)(Wv + idx);
    bf16x4 oq, ok, ov;
    oq[0] = f2bf(q.x * QSCALE); oq[1] = f2bf(q.y * QSCALE);
    oq[2] = f2bf(q.z * QSCALE); oq[3] = f2bf(q.w * QSCALE);
    ok[0] = f2bf(k.x); ok[1] = f2bf(k.y); ok[2] = f2bf(k.z); ok[3] = f2bf(k.w);
    ov[0] = f2bf(v.x); ov[1] = f2bf(v.y); ov[2] = f2bf(v.z); ov[3] = f2bf(v.w);
    *(bf16x4*)(Wqb + idx) = oq;
    *(bf16x4*)(Wkb + idx) = ok;
    *(bf16x4*)(Wvb + idx) = ov;
}

// ---------------------------------------------------------------------------
// K1: projections, split-K. Block = 16 rows; 4 waves each own a K-quarter
// (256); LDS reduce. blockIdx.y==0: Q from x; ==1: K and VR from y.
// grid (512, 2), block 256.
// ---------------------------------------------------------------------------
__global__ __launch_bounds__(256) void k_proj(
    const float* __restrict__ x, const float* __restrict__ y,
    const short* __restrict__ Wqb, const short* __restrict__ Wkb,
    const short* __restrict__ Wvb,
    const float* __restrict__ bq, const float* __restrict__ bk,
    const float* __restrict__ bv,
    short* __restrict__ Qb, short* __restrict__ Kb, short* __restrict__ VRb)
{
    const int tid = threadIdx.x, wave = tid >> 6, lane = tid & 63;
    const int r = lane & 15, half = lane >> 4;
    const int rb = blockIdx.x * 16;
    const bool isQ = (blockIdx.y == 0);
    const float* src = isQ ? x : y;
    const short* wA = isQ ? Wqb : Wkb;
    const int kq = wave * 256;

    __shared__ f32x4 red[4][8][64];

    f32x4 accA[4] = {}, accB[4] = {};
    const float* arow = src + (size_t)(rb + r) * EE + kq + half * 8;
    const short* wrow = wA + kq + half * 8;
    const short* vrow = Wvb + kq + half * 8;

    #pragma unroll
    for (int it = 0; it < 8; ++it) {
        bf16x8 a = load8(arow + it * 32, 1.0f);
        #pragma unroll
        for (int n = 0; n < 4; ++n) {
            bf16x8 b = *(const bf16x8*)(wrow + (size_t)(n * 16 + r) * EE + it * 32);
            accA[n] = mfma16(a, b, accA[n]);
        }
        if (!isQ) {
            #pragma unroll
            for (int n = 0; n < 4; ++n) {
                bf16x8 b = *(const bf16x8*)(vrow + (size_t)(n * 16 + r) * EE + it * 32);
                accB[n] = mfma16(a, b, accB[n]);
            }
        }
    }

    #pragma unroll
    for (int n = 0; n < 4; ++n) red[wave][n][lane] = accA[n];
    if (!isQ) {
        #pragma unroll
        for (int n = 0; n < 4; ++n) red[wave][4 + n][lane] = accB[n];
    }
    __syncthreads();

    const int n = wave;
    const int col = n * 16 + r;
    f32x4 s = red[0][n][lane];
    #pragma unroll
    for (int w = 1; w < 4; ++w) s += red[w][n][lane];
    float biasA = isQ ? (bq[col] * QSCALE) : bk[col];
    short* dstA = isQ ? Qb : Kb;
    #pragma unroll
    for (int ri = 0; ri < 4; ++ri)
        dstA[(size_t)(rb + half * 4 + ri) * DD + col] = f2bf(s[ri] + biasA);
    if (!isQ) {
        f32x4 t = red[0][4 + n][lane];
        #pragma unroll
        for (int w = 1; w < 4; ++w) t += red[w][4 + n][lane];
        float biasB = bv[col];
        #pragma unroll
        for (int ri = 0; ri < 4; ++ri)
            VRb[(size_t)(rb + half * 4 + ri) * DD + col] = f2bf(t[ri] + biasB);
    }
}

// ---------------------------------------------------------------------------
// K2: V^T[v][s] = sum_d WvL[v][d]*VR[s][d] + bvL[v], bf16 transposed per
// batch. grid (E/64, 8192/64), block 256.
// ---------------------------------------------------------------------------
__global__ __launch_bounds__(256) void k_vproj(
    const float* __restrict__ WvL, const float* __restrict__ bvL,
    const short* __restrict__ VRb, short* __restrict__ VT)
{
    const int tid = threadIdx.x, wave = tid >> 6, lane = tid & 63;
    const int r = lane & 15, half = lane >> 4;
    const int vb = blockIdx.x * 64;
    const int sb = blockIdx.y * 64;
    const int batch = sb >> 11, s_l = sb & (SS - 1);

    __shared__ float lds[64][68];

    f32x4 acc[4] = {};
    #pragma unroll
    for (int kk = 0; kk < 2; ++kk) {
        bf16x8 b = *(const bf16x8*)(VRb + (size_t)(sb + wave * 16 + r) * DD + kk * 32 + half * 8);
        #pragma unroll
        for (int m = 0; m < 4; ++m) {
            bf16x8 a = load8(WvL + (size_t)(vb + m * 16 + r) * DD + kk * 32 + half * 8, 1.0f);
            acc[m] = mfma16(a, b, acc[m]);
        }
    }
    const int r4 = half * 4;
    #pragma unroll
    for (int m = 0; m < 4; ++m)
        #pragma unroll
        for (int ri = 0; ri < 4; ++ri)
            lds[m * 16 + r4 + ri][wave * 16 + r] = acc[m][ri];
    __syncthreads();
    int v = tid >> 2, q4 = (tid & 3) * 16;
    float bias = bvL[vb + v];
    short* dst = VT + (size_t)batch * EE * SS + (size_t)(vb + v) * SS + s_l + q4;
    bf16x8 o0, o1;
    #pragma unroll
    for (int j = 0; j < 8; ++j) o0[j] = f2bf(lds[v][q4 + j] + bias);
    #pragma unroll
    for (int j = 0; j < 8; ++j) o1[j] = f2bf(lds[v][q4 + 8 + j] + bias);
    *(bf16x8*)dst = o0;
    *(bf16x8*)(dst + 8) = o1;
}

// ---------------------------------------------------------------------------
// K3: column softmax (over q), S-in-registers. Block = 16 k-columns; 8 waves
// x 256 q-rows. Single QK^T pass keeps all 16 S-tiles in VGPRs (64/lane);
// register max -> LDS combine -> exp2 in-register -> sum -> normalize+write
// via wave-private LDS transpose. grid (S/16, NB), block 512.
// ---------------------------------------------------------------------------
__global__ __launch_bounds__(512) void k_softmax(
    const short* __restrict__ Qb, const short* __restrict__ Kb,
    short* __restrict__ P)
{
    const int tid = threadIdx.x, wave = tid >> 6, lane = tid & 63;
    const int r = lane & 15, half = lane >> 4;
    const int batch = blockIdx.y;
    const int kb = blockIdx.x * 16;
    const short* Qp = Qb + (size_t)batch * SS * DD;
    const short* Kp = Kb + (size_t)batch * SS * DD;
    short* Pp = P + (size_t)batch * SS * SS;

    __shared__ float smax[8][16], ssum[8][16];
    __shared__ float tr[8][2][16][20];

    bf16x8 kf0 = *(const bf16x8*)(Kp + (size_t)(kb + r) * DD + half * 8);
    bf16x8 kf1 = *(const bf16x8*)(Kp + (size_t)(kb + r) * DD + 32 + half * 8);

    const int q0 = wave * 256;
    f32x4 s[16];
    #pragma unroll
    for (int t = 0; t < 16; ++t) {
        const short* pa = Qp + (size_t)(q0 + t * 16 + r) * DD;
        bf16x8 a0 = *(const bf16x8*)(pa + half * 8);
        bf16x8 a1 = *(const bf16x8*)(pa + 32 + half * 8);
        f32x4 c = {};
        c = mfma16(a0, kf0, c);
        c = mfma16(a1, kf1, c);
        s[t] = c;
    }
    float m = -1e30f;
    #pragma unroll
    for (int t = 0; t < 16; ++t)
        m = fmaxf(m, fmaxf(fmaxf(s[t][0], s[t][1]), fmaxf(s[t][2], s[t][3])));
    m = fmaxf(m, __shfl_xor(m, 16));
    m = fmaxf(m, __shfl_xor(m, 32));
    if (lane < 16) smax[wave][lane] = m;
    __syncthreads();
    float M = smax[0][r];
    #pragma unroll
    for (int w = 1; w < 8; ++w) M = fmaxf(M, smax[w][r]);

    float l = 0.f;
    #pragma unroll
    for (int t = 0; t < 16; ++t) {
        #pragma unroll
        for (int ri = 0; ri < 4; ++ri) {
            s[t][ri] = exp2f(s[t][ri] - M);
            l += s[t][ri];
        }
    }
    l += __shfl_xor(l, 16);
    l += __shfl_xor(l, 32);
    if (lane < 16) ssum[wave][lane] = l;
    __syncthreads();
    float L = 0.f;
    #pragma unroll
    for (int w = 0; w < 8; ++w) L += ssum[w][r];
    float rl = 1.0f / L;

    const int qo = lane >> 2, c4 = (lane & 3) * 4;
    #pragma unroll
    for (int t = 0; t < 16; t += 2) {
        #pragma unroll
        for (int ri = 0; ri < 4; ++ri) {
            tr[wave][0][half * 4 + ri][r] = s[t][ri] * rl;
            tr[wave][1][half * 4 + ri][r] = s[t + 1][ri] * rl;
        }
        asm volatile("s_waitcnt lgkmcnt(0)" ::: "memory");
        bf16x4 o0, o1;
        #pragma unroll
        for (int j = 0; j < 4; ++j) o0[j] = f2bf(tr[wave][0][qo][c4 + j]);
        #pragma unroll
        for (int j = 0; j < 4; ++j) o1[j] = f2bf(tr[wave][1][qo][c4 + j]);
        *(bf16x4*)(Pp + (size_t)(q0 + t * 16 + qo) * SS + kb + c4) = o0;
        *(bf16x4*)(Pp + (size_t)(q0 + t * 16 + 16 + qo) * SS + kb + c4) = o1;
        asm volatile("s_waitcnt lgkmcnt(0)" ::: "memory");
    }
}

// ---------------------------------------------------------------------------
// K4: out[q][v] = sum_k P[q][k] * VT[v][k]. 128x128 tile, BK=64, double-
// buffered LDS + global_load_lds(16B) with prefetch-before-compute (T3
// minimum 2-phase), XOR both-sides swizzle, XCD-chunked block swizzle (T1).
// grid 512 (flat), block 256.
// ---------------------------------------------------------------------------
#define PV_STAGE(buf, k0)                                                    \
    _Pragma("unroll")                                                        \
    for (int i_ = 0; i_ < 4; ++i_) {                                         \
        __builtin_amdgcn_global_load_lds(                                    \
            (const AS1 void*)(aSrc + (size_t)i_ * 32 * SS + (k0)),           \
            (AS3 void*)(As[buf] + stDst + i_ * 32 * 64), 16, 0, 0);          \
        __builtin_amdgcn_global_load_lds(                                    \
            (const AS1 void*)(bSrc + (size_t)i_ * 32 * SS + (k0)),           \
            (AS3 void*)(Bs[buf] + stDst + i_ * 32 * 64), 16, 0, 0);          \
    }

#define PV_COMPUTE(buf)                                                      \
    _Pragma("unroll")                                                        \
    for (int kk_ = 0; kk_ < 2; ++kk_) {                                      \
        const int co_ = ((kk_ * 4 + half) ^ sw) * 8;                         \
        bf16x8 a_[4], b_[4];                                                 \
        _Pragma("unroll")                                                    \
        for (int i_ = 0; i_ < 4; ++i_) {                                     \
            a_[i_] = *(const bf16x8*)(As[buf] + (wm * 64 + i_ * 16 + r) * 64 + co_); \
            b_[i_] = *(const bf16x8*)(Bs[buf] + (wn * 64 + i_ * 16 + r) * 64 + co_); \
        }                                                                    \
        _Pragma("unroll")                                                    \
        for (int mi_ = 0; mi_ < 4; ++mi_)                                    \
            _Pragma("unroll")                                                \
            for (int ni_ = 0; ni_ < 4; ++ni_)                                \
                acc[mi_][ni_] = mfma16(a_[mi_], b_[ni_], acc[mi_][ni_]);     \
    }

__global__ __launch_bounds__(256) void k_pv(
    const short* __restrict__ P, const short* __restrict__ VT,
    float* __restrict__ out)
{
    const int tid = threadIdx.x, wave = tid >> 6, lane = tid & 63;
    const int r = lane & 15, half = lane >> 4;
    const int wm = wave >> 1, wn = wave & 1;

    // XCD-chunked swizzle: 512 blocks, 8 XCDs, 64 blocks/XCD chunk. Blocks
    // sharing a P row-panel (consecutive w) land on one XCD's L2.
    const int bid = blockIdx.x;
    const int w = (bid & 7) * 64 + (bid >> 3);
    const int vx = w & 7;
    const int qy = (w >> 3) & 15;
    const int batch = w >> 7;
    const int qB = qy * 128;
    const int vB = vx * 128;
    const short* Pp = P + (size_t)batch * SS * SS;
    const short* Vp = VT + (size_t)batch * EE * SS;

    __shared__ short As[2][128 * 64];
    __shared__ short Bs[2][128 * 64];

    const int l8 = lane >> 3;
    const int cSrc = ((lane & 7) ^ l8) * 8;          // shorts, pre-swizzled src
    const short* aSrc = Pp + (size_t)(qB + wave * 8 + l8) * SS + cSrc;
    const short* bSrc = Vp + (size_t)(vB + wave * 8 + l8) * SS + cSrc;
    const int stDst = wave * 8 * 64;

    f32x4 acc[4][4] = {};
    const int sw = r & 7;

    PV_STAGE(0, 0)
    __syncthreads();
    int cur = 0;
    for (int k0 = 64; k0 < SS; k0 += 64) {
        PV_STAGE(cur ^ 1, k0)       // prefetch next tile (in flight during compute)
        PV_COMPUTE(cur)
        __syncthreads();            // drains vmcnt -> next buffer ready
        cur ^= 1;
    }
    PV_COMPUTE(cur)

    float* op = out + (size_t)batch * SS * EE;
    const int r4 = half * 4;
    #pragma unroll
    for (int mi = 0; mi < 4; ++mi)
        #pragma unroll
        for (int ni = 0; ni < 4; ++ni)
            #pragma unroll
            for (int ri = 0; ri < 4; ++ri)
                op[(size_t)(qB + wm * 64 + mi * 16 + r4 + ri) * EE + vB + wn * 64 + ni * 16 + r] = acc[mi][ni][ri];
}

// ---------------------------------------------------------------------------
extern "C" void kernel_launch(void* const* d_in, const int* in_sizes, int n_in,
                              void* d_out, int out_size, void* d_ws, size_t ws_size,
                              hipStream_t stream) {
    (void)in_sizes; (void)n_in; (void)out_size; (void)ws_size;
    const float* x   = (const float*)d_in[0];
    const float* y   = (const float*)d_in[1];
    const float* Wq  = (const float*)d_in[2];
    const float* bq  = (const float*)d_in[3];
    const float* Wk  = (const float*)d_in[4];
    const float* bk  = (const float*)d_in[5];
    const float* WvR = (const float*)d_in[6];
    const float* bvR = (const float*)d_in[7];
    const float* WvL = (const float*)d_in[8];
    const float* bvL = (const float*)d_in[9];
    float* out = (float*)d_out;

    short* Qb  = (short*)d_ws;
    short* Kb  = Qb  + (size_t)MTOT * DD;
    short* VRb = Kb  + (size_t)MTOT * DD;
    short* VT  = VRb + (size_t)MTOT * DD;
    short* Pb  = VT  + (size_t)NB * EE * SS;
    short* Wqb = Pb  + (size_t)NB * SS * SS;
    short* Wkb = Wqb + (size_t)DD * EE;
    short* Wvb = Wkb + (size_t)DD * EE;

    k_prep<<<dim3(DD * EE / 1024), 256, 0, stream>>>(Wq, Wk, WvR, Wqb, Wkb, Wvb);
    k_proj<<<dim3(MTOT / 16, 2), 256, 0, stream>>>(x, y, Wqb, Wkb, Wvb, bq, bk, bvR, Qb, Kb, VRb);
    k_vproj<<<dim3(EE / 64, MTOT / 64), 256, 0, stream>>>(WvL, bvL, VRb, VT);
    k_softmax<<<dim3(SS / 16, NB), 512, 0, stream>>>(Qb, Kb, Pb);
    k_pv<<<dim3(512), 256, 0, stream>>>(Pb, VT, out);
}

// Round 5
// 127.314 us; speedup vs baseline: 2.2028x; 1.0896x over previous
//
#include <hip/hip_runtime.h>
#include <hip/hip_bf16.h>

#define DEV static __device__ __forceinline__
#define AS1 __attribute__((address_space(1)))
#define AS3 __attribute__((address_space(3)))

typedef __attribute__((ext_vector_type(8))) short bf16x8;
typedef __attribute__((ext_vector_type(4))) short bf16x4;
typedef __attribute__((ext_vector_type(4))) float f32x4;

constexpr int NB = 4;        // batches
constexpr int SS = 2048;     // seq
constexpr int EE = 1024;     // embed
constexpr int DD = 64;       // low-rank d
constexpr int MTOT = NB * SS;  // 8192 rows total

// Q is pre-scaled by 1/sqrt(D) * log2(e) so softmax runs in exp2 domain.
#define QSCALE (0.125f * 1.44269504088896340736f)

DEV short f2bf(float f) {
    union { float f; unsigned u; } v; v.f = f;
    unsigned u = v.u;
    u += 0x7FFFu + ((u >> 16) & 1u);   // RNE
    return (short)(u >> 16);
}

DEV bf16x8 load8(const float* p, float s) {   // p must be 16B aligned
    float4 u = *(const float4*)(p);
    float4 v = *(const float4*)(p + 4);
    bf16x8 r;
    r[0] = f2bf(u.x * s); r[1] = f2bf(u.y * s); r[2] = f2bf(u.z * s); r[3] = f2bf(u.w * s);
    r[4] = f2bf(v.x * s); r[5] = f2bf(v.y * s); r[6] = f2bf(v.z * s); r[7] = f2bf(v.w * s);
    return r;
}

DEV f32x4 mfma16(bf16x8 a, bf16x8 b, f32x4 c) {
    return __builtin_amdgcn_mfma_f32_16x16x32_bf16(a, b, c, 0, 0, 0);
}

DEV float redmax16(float v) {
    v = fmaxf(v, __shfl_xor(v, 1)); v = fmaxf(v, __shfl_xor(v, 2));
    v = fmaxf(v, __shfl_xor(v, 4)); v = fmaxf(v, __shfl_xor(v, 8));
    return v;
}
DEV float redsum16(float v) {
    v += __shfl_xor(v, 1); v += __shfl_xor(v, 2);
    v += __shfl_xor(v, 4); v += __shfl_xor(v, 8);
    return v;
}

// ---------------------------------------------------------------------------
// K0: pre-convert projection weights to bf16 (Wq scaled by QSCALE).
// ---------------------------------------------------------------------------
__global__ __launch_bounds__(256) void k_prep(
    const float* __restrict__ Wq, const float* __restrict__ Wk,
    const float* __restrict__ Wv,
    short* __restrict__ Wqb, short* __restrict__ Wkb, short* __restrict__ Wvb)
{
    int idx = (blockIdx.x * 256 + threadIdx.x) * 4;
    float4 q = *(const float4*)(Wq + idx);
    float4 k = *(const float4*)(Wk + idx);
    float4 v = *(const float4*)(Wv + idx);
    bf16x4 oq, ok, ov;
    oq[0] = f2bf(q.x * QSCALE); oq[1] = f2bf(q.y * QSCALE);
    oq[2] = f2bf(q.z * QSCALE); oq[3] = f2bf(q.w * QSCALE);
    ok[0] = f2bf(k.x); ok[1] = f2bf(k.y); ok[2] = f2bf(k.z); ok[3] = f2bf(k.w);
    ov[0] = f2bf(v.x); ov[1] = f2bf(v.y); ov[2] = f2bf(v.z); ov[3] = f2bf(v.w);
    *(bf16x4*)(Wqb + idx) = oq;
    *(bf16x4*)(Wkb + idx) = ok;
    *(bf16x4*)(Wvb + idx) = ov;
}

// ---------------------------------------------------------------------------
// K1: projections, split-K. Block = 16 rows; 4 waves each own a K-quarter
// (256); LDS reduce. blockIdx.y==0: Q from x; ==1: K and VR from y.
// grid (512, 2), block 256.
// ---------------------------------------------------------------------------
__global__ __launch_bounds__(256) void k_proj(
    const float* __restrict__ x, const float* __restrict__ y,
    const short* __restrict__ Wqb, const short* __restrict__ Wkb,
    const short* __restrict__ Wvb,
    const float* __restrict__ bq, const float* __restrict__ bk,
    const float* __restrict__ bv,
    short* __restrict__ Qb, short* __restrict__ Kb, short* __restrict__ VRb)
{
    const int tid = threadIdx.x, wave = tid >> 6, lane = tid & 63;
    const int r = lane & 15, half = lane >> 4;
    const int rb = blockIdx.x * 16;
    const bool isQ = (blockIdx.y == 0);
    const float* src = isQ ? x : y;
    const short* wA = isQ ? Wqb : Wkb;
    const int kq = wave * 256;

    __shared__ f32x4 red[4][8][64];

    f32x4 accA[4] = {}, accB[4] = {};
    const float* arow = src + (size_t)(rb + r) * EE + kq + half * 8;
    const short* wrow = wA + kq + half * 8;
    const short* vrow = Wvb + kq + half * 8;

    #pragma unroll
    for (int it = 0; it < 8; ++it) {
        bf16x8 a = load8(arow + it * 32, 1.0f);
        #pragma unroll
        for (int n = 0; n < 4; ++n) {
            bf16x8 b = *(const bf16x8*)(wrow + (size_t)(n * 16 + r) * EE + it * 32);
            accA[n] = mfma16(a, b, accA[n]);
        }
        if (!isQ) {
            #pragma unroll
            for (int n = 0; n < 4; ++n) {
                bf16x8 b = *(const bf16x8*)(vrow + (size_t)(n * 16 + r) * EE + it * 32);
                accB[n] = mfma16(a, b, accB[n]);
            }
        }
    }

    #pragma unroll
    for (int n = 0; n < 4; ++n) red[wave][n][lane] = accA[n];
    if (!isQ) {
        #pragma unroll
        for (int n = 0; n < 4; ++n) red[wave][4 + n][lane] = accB[n];
    }
    __syncthreads();

    const int n = wave;
    const int col = n * 16 + r;
    f32x4 s = red[0][n][lane];
    #pragma unroll
    for (int w = 1; w < 4; ++w) s += red[w][n][lane];
    float biasA = isQ ? (bq[col] * QSCALE) : bk[col];
    short* dstA = isQ ? Qb : Kb;
    #pragma unroll
    for (int ri = 0; ri < 4; ++ri)
        dstA[(size_t)(rb + half * 4 + ri) * DD + col] = f2bf(s[ri] + biasA);
    if (!isQ) {
        f32x4 t = red[0][4 + n][lane];
        #pragma unroll
        for (int w = 1; w < 4; ++w) t += red[w][4 + n][lane];
        float biasB = bv[col];
        #pragma unroll
        for (int ri = 0; ri < 4; ++ri)
            VRb[(size_t)(rb + half * 4 + ri) * DD + col] = f2bf(t[ri] + biasB);
    }
}

// ---------------------------------------------------------------------------
// K2: V^T[v][s] = sum_d WvL[v][d]*VR[s][d] + bvL[v], bf16 transposed per
// batch. grid (E/64, 8192/64), block 256.
// ---------------------------------------------------------------------------
__global__ __launch_bounds__(256) void k_vproj(
    const float* __restrict__ WvL, const float* __restrict__ bvL,
    const short* __restrict__ VRb, short* __restrict__ VT)
{
    const int tid = threadIdx.x, wave = tid >> 6, lane = tid & 63;
    const int r = lane & 15, half = lane >> 4;
    const int vb = blockIdx.x * 64;
    const int sb = blockIdx.y * 64;
    const int batch = sb >> 11, s_l = sb & (SS - 1);

    __shared__ float lds[64][68];

    f32x4 acc[4] = {};
    #pragma unroll
    for (int kk = 0; kk < 2; ++kk) {
        bf16x8 b = *(const bf16x8*)(VRb + (size_t)(sb + wave * 16 + r) * DD + kk * 32 + half * 8);
        #pragma unroll
        for (int m = 0; m < 4; ++m) {
            bf16x8 a = load8(WvL + (size_t)(vb + m * 16 + r) * DD + kk * 32 + half * 8, 1.0f);
            acc[m] = mfma16(a, b, acc[m]);
        }
    }
    const int r4 = half * 4;
    #pragma unroll
    for (int m = 0; m < 4; ++m)
        #pragma unroll
        for (int ri = 0; ri < 4; ++ri)
            lds[m * 16 + r4 + ri][wave * 16 + r] = acc[m][ri];
    __syncthreads();
    int v = tid >> 2, q4 = (tid & 3) * 16;
    float bias = bvL[vb + v];
    short* dst = VT + (size_t)batch * EE * SS + (size_t)(vb + v) * SS + s_l + q4;
    bf16x8 o0, o1;
    #pragma unroll
    for (int j = 0; j < 8; ++j) o0[j] = f2bf(lds[v][q4 + j] + bias);
    #pragma unroll
    for (int j = 0; j < 8; ++j) o1[j] = f2bf(lds[v][q4 + 8 + j] + bias);
    *(bf16x8*)dst = o0;
    *(bf16x8*)(dst + 8) = o1;
}

// ---------------------------------------------------------------------------
// K3 v4: column softmax (over q) with swapped MFMA: S^T-frags. mfma(K,Q)
// puts P[q=col][k=half*4+ri] in each lane -> q-reduce = 4 shfl_xor over r,
// and P-row writes are direct 8B stores (no LDS transpose, no waits).
// Block = 16 k-cols; 8 waves x 256 q-rows. grid (S/16, NB), block 512.
// ---------------------------------------------------------------------------
__global__ __launch_bounds__(512) void k_softmax(
    const short* __restrict__ Qb, const short* __restrict__ Kb,
    short* __restrict__ P)
{
    const int tid = threadIdx.x, wave = tid >> 6, lane = tid & 63;
    const int r = lane & 15, half = lane >> 4;
    const int batch = blockIdx.y;
    const int kb = blockIdx.x * 16;
    const short* Qp = Qb + (size_t)batch * SS * DD;
    const short* Kp = Kb + (size_t)batch * SS * DD;
    short* Pp = P + (size_t)batch * SS * SS;

    __shared__ float smax[8][16], ssum[8][16];

    // A-operand = K rows (16 k), contiguous d
    bf16x8 kf0 = *(const bf16x8*)(Kp + (size_t)(kb + r) * DD + half * 8);
    bf16x8 kf1 = *(const bf16x8*)(Kp + (size_t)(kb + r) * DD + 32 + half * 8);

    const int q0 = wave * 256;
    f32x4 s[16];
    #pragma unroll
    for (int t = 0; t < 16; ++t) {
        const short* pa = Qp + (size_t)(q0 + t * 16 + r) * DD;
        bf16x8 a0 = *(const bf16x8*)(pa + half * 8);
        bf16x8 a1 = *(const bf16x8*)(pa + 32 + half * 8);
        f32x4 c = {};
        c = mfma16(kf0, a0, c);   // swapped: col=q(r), row=k(half*4+ri)
        c = mfma16(kf1, a1, c);
        s[t] = c;
    }
    // per-lane max over its 16 q-values, per k-component
    f32x4 m4 = s[0];
    #pragma unroll
    for (int t = 1; t < 16; ++t) {
        #pragma unroll
        for (int ri = 0; ri < 4; ++ri) m4[ri] = fmaxf(m4[ri], s[t][ri]);
    }
    #pragma unroll
    for (int ri = 0; ri < 4; ++ri) m4[ri] = redmax16(m4[ri]);
    if (r == 0) {
        #pragma unroll
        for (int ri = 0; ri < 4; ++ri) smax[wave][half * 4 + ri] = m4[ri];
    }
    __syncthreads();
    f32x4 M;
    #pragma unroll
    for (int ri = 0; ri < 4; ++ri) {
        float v = smax[0][half * 4 + ri];
        #pragma unroll
        for (int w = 1; w < 8; ++w) v = fmaxf(v, smax[w][half * 4 + ri]);
        M[ri] = v;
    }

    f32x4 l4 = {};
    #pragma unroll
    for (int t = 0; t < 16; ++t) {
        #pragma unroll
        for (int ri = 0; ri < 4; ++ri) {
            s[t][ri] = exp2f(s[t][ri] - M[ri]);
            l4[ri] += s[t][ri];
        }
    }
    #pragma unroll
    for (int ri = 0; ri < 4; ++ri) l4[ri] = redsum16(l4[ri]);
    if (r == 0) {
        #pragma unroll
        for (int ri = 0; ri < 4; ++ri) ssum[wave][half * 4 + ri] = l4[ri];
    }
    __syncthreads();
    f32x4 rl;
    #pragma unroll
    for (int ri = 0; ri < 4; ++ri) {
        float v = 0.f;
        #pragma unroll
        for (int w = 0; w < 8; ++w) v += ssum[w][half * 4 + ri];
        rl[ri] = 1.0f / v;
    }

    #pragma unroll
    for (int t = 0; t < 16; ++t) {
        bf16x4 o;
        #pragma unroll
        for (int ri = 0; ri < 4; ++ri) o[ri] = f2bf(s[t][ri] * rl[ri]);
        *(bf16x4*)(Pp + (size_t)(q0 + t * 16 + r) * SS + kb + half * 4) = o;
    }
}

// ---------------------------------------------------------------------------
// K4: out[q][v] = sum_k P[q][k] * VT[v][k]. 128x128 tile, BK=64, statically
// double-buffered LDS (As0/Bs0, As1/Bs1 — compile-time addresses), prefetch-
// before-compute, XOR both-sides swizzle, XCD-chunked swizzle, setprio around
// MFMA. grid 512 (flat), block 256.
// ---------------------------------------------------------------------------
#define PV_STAGE(AD, BD, k0)                                                 \
    _Pragma("unroll")                                                        \
    for (int i_ = 0; i_ < 4; ++i_) {                                         \
        __builtin_amdgcn_global_load_lds(                                    \
            (const AS1 void*)(aSrc + (size_t)i_ * 32 * SS + (k0)),           \
            (AS3 void*)(AD + stDst + i_ * 32 * 64), 16, 0, 0);               \
        __builtin_amdgcn_global_load_lds(                                    \
            (const AS1 void*)(bSrc + (size_t)i_ * 32 * SS + (k0)),           \
            (AS3 void*)(BD + stDst + i_ * 32 * 64), 16, 0, 0);               \
    }

#define PV_COMPUTE(AS_, BS_)                                                 \
    __builtin_amdgcn_s_setprio(1);                                           \
    _Pragma("unroll")                                                        \
    for (int kk_ = 0; kk_ < 2; ++kk_) {                                      \
        const int co_ = ((kk_ * 4 + half) ^ sw) * 8;                         \
        bf16x8 a_[4], b_[4];                                                 \
        _Pragma("unroll")                                                    \
        for (int i_ = 0; i_ < 4; ++i_) {                                     \
            a_[i_] = *(const bf16x8*)(AS_ + (wm * 64 + i_ * 16 + r) * 64 + co_); \
            b_[i_] = *(const bf16x8*)(BS_ + (wn * 64 + i_ * 16 + r) * 64 + co_); \
        }                                                                    \
        _Pragma("unroll")                                                    \
        for (int mi_ = 0; mi_ < 4; ++mi_)                                    \
            _Pragma("unroll")                                                \
            for (int ni_ = 0; ni_ < 4; ++ni_)                                \
                acc[mi_][ni_] = mfma16(a_[mi_], b_[ni_], acc[mi_][ni_]);     \
    }                                                                        \
    __builtin_amdgcn_s_setprio(0);

__global__ __launch_bounds__(256) void k_pv(
    const short* __restrict__ P, const short* __restrict__ VT,
    float* __restrict__ out)
{
    const int tid = threadIdx.x, wave = tid >> 6, lane = tid & 63;
    const int r = lane & 15, half = lane >> 4;
    const int wm = wave >> 1, wn = wave & 1;

    // XCD-chunked swizzle: 512 blocks, 8 XCDs, 64 blocks/XCD chunk. Blocks
    // sharing a P row-panel (consecutive w) land on one XCD's L2.
    const int bid = blockIdx.x;
    const int w = (bid & 7) * 64 + (bid >> 3);
    const int vx = w & 7;
    const int qy = (w >> 3) & 15;
    const int batch = w >> 7;
    const int qB = qy * 128;
    const int vB = vx * 128;
    const short* Pp = P + (size_t)batch * SS * SS;
    const short* Vp = VT + (size_t)batch * EE * SS;

    __shared__ short As0[128 * 64];
    __shared__ short Bs0[128 * 64];
    __shared__ short As1[128 * 64];
    __shared__ short Bs1[128 * 64];

    const int l8 = lane >> 3;
    const int cSrc = ((lane & 7) ^ l8) * 8;          // shorts, pre-swizzled src
    const short* aSrc = Pp + (size_t)(qB + wave * 8 + l8) * SS + cSrc;
    const short* bSrc = Vp + (size_t)(vB + wave * 8 + l8) * SS + cSrc;
    const int stDst = wave * 8 * 64;

    f32x4 acc[4][4] = {};
    const int sw = r & 7;

    PV_STAGE(As0, Bs0, 0)
    __syncthreads();
    for (int k0 = 0; k0 < SS; k0 += 128) {
        PV_STAGE(As1, Bs1, k0 + 64)          // prefetch odd tile
        PV_COMPUTE(As0, Bs0)
        __syncthreads();                     // drain: As1/Bs1 ready, As0 free
        if (k0 + 128 < SS) PV_STAGE(As0, Bs0, k0 + 128)  // prefetch even tile
        PV_COMPUTE(As1, Bs1)
        __syncthreads();
    }

    float* op = out + (size_t)batch * SS * EE;
    const int r4 = half * 4;
    #pragma unroll
    for (int mi = 0; mi < 4; ++mi)
        #pragma unroll
        for (int ni = 0; ni < 4; ++ni)
            #pragma unroll
            for (int ri = 0; ri < 4; ++ri)
                op[(size_t)(qB + wm * 64 + mi * 16 + r4 + ri) * EE + vB + wn * 64 + ni * 16 + r] = acc[mi][ni][ri];
}

// ---------------------------------------------------------------------------
extern "C" void kernel_launch(void* const* d_in, const int* in_sizes, int n_in,
                              void* d_out, int out_size, void* d_ws, size_t ws_size,
                              hipStream_t stream) {
    (void)in_sizes; (void)n_in; (void)out_size; (void)ws_size;
    const float* x   = (const float*)d_in[0];
    const float* y   = (const float*)d_in[1];
    const float* Wq  = (const float*)d_in[2];
    const float* bq  = (const float*)d_in[3];
    const float* Wk  = (const float*)d_in[4];
    const float* bk  = (const float*)d_in[5];
    const float* WvR = (const float*)d_in[6];
    const float* bvR = (const float*)d_in[7];
    const float* WvL = (const float*)d_in[8];
    const float* bvL = (const float*)d_in[9];
    float* out = (float*)d_out;

    short* Qb  = (short*)d_ws;
    short* Kb  = Qb  + (size_t)MTOT * DD;
    short* VRb = Kb  + (size_t)MTOT * DD;
    short* VT  = VRb + (size_t)MTOT * DD;
    short* Pb  = VT  + (size_t)NB * EE * SS;
    short* Wqb = Pb  + (size_t)NB * SS * SS;
    short* Wkb = Wqb + (size_t)DD * EE;
    short* Wvb = Wkb + (size_t)DD * EE;

    k_prep<<<dim3(DD * EE / 1024), 256, 0, stream>>>(Wq, Wk, WvR, Wqb, Wkb, Wvb);
    k_proj<<<dim3(MTOT / 16, 2), 256, 0, stream>>>(x, y, Wqb, Wkb, Wvb, bq, bk, bvR, Qb, Kb, VRb);
    k_vproj<<<dim3(EE / 64, MTOT / 64), 256, 0, stream>>>(WvL, bvL, VRb, VT);
    k_softmax<<<dim3(SS / 16, NB), 512, 0, stream>>>(Qb, Kb, Pb);
    k_pv<<<dim3(512), 256, 0, stream>>>(Pb, VT, out);
}

// Round 6
// 126.752 us; speedup vs baseline: 2.2125x; 1.0044x over previous
//
#include <hip/hip_runtime.h>
#include <hip/hip_bf16.h>

#define DEV static __device__ __forceinline__
#define AS1 __attribute__((address_space(1)))
#define AS3 __attribute__((address_space(3)))

typedef __attribute__((ext_vector_type(8))) short bf16x8;
typedef __attribute__((ext_vector_type(4))) short bf16x4;
typedef __attribute__((ext_vector_type(4))) float f32x4;

constexpr int NB = 4;        // batches
constexpr int SS = 2048;     // seq
constexpr int EE = 1024;     // embed
constexpr int DD = 64;       // low-rank d
constexpr int MTOT = NB * SS;  // 8192 rows total

// Q is pre-scaled by 1/sqrt(D) * log2(e) so softmax runs in exp2 domain.
#define QSCALE (0.125f * 1.44269504088896340736f)

DEV short f2bf(float f) {
    union { float f; unsigned u; } v; v.f = f;
    unsigned u = v.u;
    u += 0x7FFFu + ((u >> 16) & 1u);   // RNE
    return (short)(u >> 16);
}

DEV bf16x8 load8(const float* p, float s) {   // p must be 16B aligned
    float4 u = *(const float4*)(p);
    float4 v = *(const float4*)(p + 4);
    bf16x8 r;
    r[0] = f2bf(u.x * s); r[1] = f2bf(u.y * s); r[2] = f2bf(u.z * s); r[3] = f2bf(u.w * s);
    r[4] = f2bf(v.x * s); r[5] = f2bf(v.y * s); r[6] = f2bf(v.z * s); r[7] = f2bf(v.w * s);
    return r;
}

DEV f32x4 mfma16(bf16x8 a, bf16x8 b, f32x4 c) {
    return __builtin_amdgcn_mfma_f32_16x16x32_bf16(a, b, c, 0, 0, 0);
}

DEV float redmax16(float v) {
    v = fmaxf(v, __shfl_xor(v, 1)); v = fmaxf(v, __shfl_xor(v, 2));
    v = fmaxf(v, __shfl_xor(v, 4)); v = fmaxf(v, __shfl_xor(v, 8));
    return v;
}
DEV float redsum16(float v) {
    v += __shfl_xor(v, 1); v += __shfl_xor(v, 2);
    v += __shfl_xor(v, 4); v += __shfl_xor(v, 8);
    return v;
}

// ---------------------------------------------------------------------------
// K0: pre-convert projection weights to bf16 (Wq scaled by QSCALE).
// ---------------------------------------------------------------------------
__global__ __launch_bounds__(256) void k_prep(
    const float* __restrict__ Wq, const float* __restrict__ Wk,
    const float* __restrict__ Wv,
    short* __restrict__ Wqb, short* __restrict__ Wkb, short* __restrict__ Wvb)
{
    int idx = (blockIdx.x * 256 + threadIdx.x) * 4;
    float4 q = *(const float4*)(Wq + idx);
    float4 k = *(const float4*)(Wk + idx);
    float4 v = *(const float4*)(Wv + idx);
    bf16x4 oq, ok, ov;
    oq[0] = f2bf(q.x * QSCALE); oq[1] = f2bf(q.y * QSCALE);
    oq[2] = f2bf(q.z * QSCALE); oq[3] = f2bf(q.w * QSCALE);
    ok[0] = f2bf(k.x); ok[1] = f2bf(k.y); ok[2] = f2bf(k.z); ok[3] = f2bf(k.w);
    ov[0] = f2bf(v.x); ov[1] = f2bf(v.y); ov[2] = f2bf(v.z); ov[3] = f2bf(v.w);
    *(bf16x4*)(Wqb + idx) = oq;
    *(bf16x4*)(Wkb + idx) = ok;
    *(bf16x4*)(Wvb + idx) = ov;
}

// ---------------------------------------------------------------------------
// K1 v3: projections, split-K, A-prefetch-all. Block = 16 rows; 4 waves each
// own a K-quarter (256). All 16 A-chunk loads issue before the MFMA loop
// (latency-bound fix: 48-VGPR serialization -> 16 outstanding dwordx4/lane).
// LDS reduce. blockIdx.y==0: Q from x; ==1: K and VR from y.
// grid (512, 2), block 256.
// ---------------------------------------------------------------------------
__global__ __launch_bounds__(256) void k_proj(
    const float* __restrict__ x, const float* __restrict__ y,
    const short* __restrict__ Wqb, const short* __restrict__ Wkb,
    const short* __restrict__ Wvb,
    const float* __restrict__ bq, const float* __restrict__ bk,
    const float* __restrict__ bv,
    short* __restrict__ Qb, short* __restrict__ Kb, short* __restrict__ VRb)
{
    const int tid = threadIdx.x, wave = tid >> 6, lane = tid & 63;
    const int r = lane & 15, half = lane >> 4;
    const int rb = blockIdx.x * 16;
    const bool isQ = (blockIdx.y == 0);
    const float* src = isQ ? x : y;
    const short* wA = isQ ? Wqb : Wkb;
    const int kq = wave * 256;

    __shared__ f32x4 red[4][8][64];

    f32x4 accA[4] = {}, accB[4] = {};
    const float* arow = src + (size_t)(rb + r) * EE + kq + half * 8;
    const short* wrow = wA + kq + half * 8;
    const short* vrow = Wvb + kq + half * 8;

    // issue ALL 16 A-loads up front (64 VGPRs live) — Little's-law fix
    float4 af0[8], af1[8];
    #pragma unroll
    for (int it = 0; it < 8; ++it) {
        af0[it] = *(const float4*)(arow + it * 32);
        af1[it] = *(const float4*)(arow + it * 32 + 4);
    }

    #pragma unroll
    for (int it = 0; it < 8; ++it) {
        bf16x8 a;
        a[0] = f2bf(af0[it].x); a[1] = f2bf(af0[it].y);
        a[2] = f2bf(af0[it].z); a[3] = f2bf(af0[it].w);
        a[4] = f2bf(af1[it].x); a[5] = f2bf(af1[it].y);
        a[6] = f2bf(af1[it].z); a[7] = f2bf(af1[it].w);
        #pragma unroll
        for (int n = 0; n < 4; ++n) {
            bf16x8 b = *(const bf16x8*)(wrow + (size_t)(n * 16 + r) * EE + it * 32);
            accA[n] = mfma16(a, b, accA[n]);
        }
        if (!isQ) {
            #pragma unroll
            for (int n = 0; n < 4; ++n) {
                bf16x8 b = *(const bf16x8*)(vrow + (size_t)(n * 16 + r) * EE + it * 32);
                accB[n] = mfma16(a, b, accB[n]);
            }
        }
    }

    #pragma unroll
    for (int n = 0; n < 4; ++n) red[wave][n][lane] = accA[n];
    if (!isQ) {
        #pragma unroll
        for (int n = 0; n < 4; ++n) red[wave][4 + n][lane] = accB[n];
    }
    __syncthreads();

    const int n = wave;
    const int col = n * 16 + r;
    f32x4 s = red[0][n][lane];
    #pragma unroll
    for (int w = 1; w < 4; ++w) s += red[w][n][lane];
    float biasA = isQ ? (bq[col] * QSCALE) : bk[col];
    short* dstA = isQ ? Qb : Kb;
    #pragma unroll
    for (int ri = 0; ri < 4; ++ri)
        dstA[(size_t)(rb + half * 4 + ri) * DD + col] = f2bf(s[ri] + biasA);
    if (!isQ) {
        f32x4 t = red[0][4 + n][lane];
        #pragma unroll
        for (int w = 1; w < 4; ++w) t += red[w][4 + n][lane];
        float biasB = bv[col];
        #pragma unroll
        for (int ri = 0; ri < 4; ++ri)
            VRb[(size_t)(rb + half * 4 + ri) * DD + col] = f2bf(t[ri] + biasB);
    }
}

// ---------------------------------------------------------------------------
// K2: V^T[v][s] = sum_d WvL[v][d]*VR[s][d] + bvL[v], bf16 transposed per
// batch. grid (E/64, 8192/64), block 256.
// ---------------------------------------------------------------------------
__global__ __launch_bounds__(256) void k_vproj(
    const float* __restrict__ WvL, const float* __restrict__ bvL,
    const short* __restrict__ VRb, short* __restrict__ VT)
{
    const int tid = threadIdx.x, wave = tid >> 6, lane = tid & 63;
    const int r = lane & 15, half = lane >> 4;
    const int vb = blockIdx.x * 64;
    const int sb = blockIdx.y * 64;
    const int batch = sb >> 11, s_l = sb & (SS - 1);

    __shared__ float lds[64][68];

    f32x4 acc[4] = {};
    #pragma unroll
    for (int kk = 0; kk < 2; ++kk) {
        bf16x8 b = *(const bf16x8*)(VRb + (size_t)(sb + wave * 16 + r) * DD + kk * 32 + half * 8);
        #pragma unroll
        for (int m = 0; m < 4; ++m) {
            bf16x8 a = load8(WvL + (size_t)(vb + m * 16 + r) * DD + kk * 32 + half * 8, 1.0f);
            acc[m] = mfma16(a, b, acc[m]);
        }
    }
    const int r4 = half * 4;
    #pragma unroll
    for (int m = 0; m < 4; ++m)
        #pragma unroll
        for (int ri = 0; ri < 4; ++ri)
            lds[m * 16 + r4 + ri][wave * 16 + r] = acc[m][ri];
    __syncthreads();
    int v = tid >> 2, q4 = (tid & 3) * 16;
    float bias = bvL[vb + v];
    short* dst = VT + (size_t)batch * EE * SS + (size_t)(vb + v) * SS + s_l + q4;
    bf16x8 o0, o1;
    #pragma unroll
    for (int j = 0; j < 8; ++j) o0[j] = f2bf(lds[v][q4 + j] + bias);
    #pragma unroll
    for (int j = 0; j < 8; ++j) o1[j] = f2bf(lds[v][q4 + 8 + j] + bias);
    *(bf16x8*)dst = o0;
    *(bf16x8*)(dst + 8) = o1;
}

// ---------------------------------------------------------------------------
// K3 v4: column softmax (over q) with swapped MFMA: S^T-frags. mfma(K,Q)
// puts P[q=col][k=half*4+ri] in each lane -> q-reduce = 4 shfl_xor over r,
// and P-row writes are direct 8B stores (no LDS transpose, no waits).
// Block = 16 k-cols; 8 waves x 256 q-rows. grid (S/16, NB), block 512.
// ---------------------------------------------------------------------------
__global__ __launch_bounds__(512) void k_softmax(
    const short* __restrict__ Qb, const short* __restrict__ Kb,
    short* __restrict__ P)
{
    const int tid = threadIdx.x, wave = tid >> 6, lane = tid & 63;
    const int r = lane & 15, half = lane >> 4;
    const int batch = blockIdx.y;
    const int kb = blockIdx.x * 16;
    const short* Qp = Qb + (size_t)batch * SS * DD;
    const short* Kp = Kb + (size_t)batch * SS * DD;
    short* Pp = P + (size_t)batch * SS * SS;

    __shared__ float smax[8][16], ssum[8][16];

    // A-operand = K rows (16 k), contiguous d
    bf16x8 kf0 = *(const bf16x8*)(Kp + (size_t)(kb + r) * DD + half * 8);
    bf16x8 kf1 = *(const bf16x8*)(Kp + (size_t)(kb + r) * DD + 32 + half * 8);

    const int q0 = wave * 256;
    f32x4 s[16];
    #pragma unroll
    for (int t = 0; t < 16; ++t) {
        const short* pa = Qp + (size_t)(q0 + t * 16 + r) * DD;
        bf16x8 a0 = *(const bf16x8*)(pa + half * 8);
        bf16x8 a1 = *(const bf16x8*)(pa + 32 + half * 8);
        f32x4 c = {};
        c = mfma16(kf0, a0, c);   // swapped: col=q(r), row=k(half*4+ri)
        c = mfma16(kf1, a1, c);
        s[t] = c;
    }
    // per-lane max over its 16 q-values, per k-component
    f32x4 m4 = s[0];
    #pragma unroll
    for (int t = 1; t < 16; ++t) {
        #pragma unroll
        for (int ri = 0; ri < 4; ++ri) m4[ri] = fmaxf(m4[ri], s[t][ri]);
    }
    #pragma unroll
    for (int ri = 0; ri < 4; ++ri) m4[ri] = redmax16(m4[ri]);
    if (r == 0) {
        #pragma unroll
        for (int ri = 0; ri < 4; ++ri) smax[wave][half * 4 + ri] = m4[ri];
    }
    __syncthreads();
    f32x4 M;
    #pragma unroll
    for (int ri = 0; ri < 4; ++ri) {
        float v = smax[0][half * 4 + ri];
        #pragma unroll
        for (int w = 1; w < 8; ++w) v = fmaxf(v, smax[w][half * 4 + ri]);
        M[ri] = v;
    }

    f32x4 l4 = {};
    #pragma unroll
    for (int t = 0; t < 16; ++t) {
        #pragma unroll
        for (int ri = 0; ri < 4; ++ri) {
            s[t][ri] = exp2f(s[t][ri] - M[ri]);
            l4[ri] += s[t][ri];
        }
    }
    #pragma unroll
    for (int ri = 0; ri < 4; ++ri) l4[ri] = redsum16(l4[ri]);
    if (r == 0) {
        #pragma unroll
        for (int ri = 0; ri < 4; ++ri) ssum[wave][half * 4 + ri] = l4[ri];
    }
    __syncthreads();
    f32x4 rl;
    #pragma unroll
    for (int ri = 0; ri < 4; ++ri) {
        float v = 0.f;
        #pragma unroll
        for (int w = 0; w < 8; ++w) v += ssum[w][half * 4 + ri];
        rl[ri] = 1.0f / v;
    }

    #pragma unroll
    for (int t = 0; t < 16; ++t) {
        bf16x4 o;
        #pragma unroll
        for (int ri = 0; ri < 4; ++ri) o[ri] = f2bf(s[t][ri] * rl[ri]);
        *(bf16x4*)(Pp + (size_t)(q0 + t * 16 + r) * SS + kb + half * 4) = o;
    }
}

// ---------------------------------------------------------------------------
// K4: out[q][v] = sum_k P[q][k] * VT[v][k]. 128x128 tile, BK=64, statically
// double-buffered LDS (As0/Bs0, As1/Bs1 — compile-time addresses), prefetch-
// before-compute, XOR both-sides swizzle, XCD-chunked swizzle, setprio around
// MFMA. grid 512 (flat), block 256.
// ---------------------------------------------------------------------------
#define PV_STAGE(AD, BD, k0)                                                 \
    _Pragma("unroll")                                                        \
    for (int i_ = 0; i_ < 4; ++i_) {                                         \
        __builtin_amdgcn_global_load_lds(                                    \
            (const AS1 void*)(aSrc + (size_t)i_ * 32 * SS + (k0)),           \
            (AS3 void*)(AD + stDst + i_ * 32 * 64), 16, 0, 0);               \
        __builtin_amdgcn_global_load_lds(                                    \
            (const AS1 void*)(bSrc + (size_t)i_ * 32 * SS + (k0)),           \
            (AS3 void*)(BD + stDst + i_ * 32 * 64), 16, 0, 0);               \
    }

#define PV_COMPUTE(AS_, BS_)                                                 \
    __builtin_amdgcn_s_setprio(1);                                           \
    _Pragma("unroll")                                                        \
    for (int kk_ = 0; kk_ < 2; ++kk_) {                                      \
        const int co_ = ((kk_ * 4 + half) ^ sw) * 8;                         \
        bf16x8 a_[4], b_[4];                                                 \
        _Pragma("unroll")                                                    \
        for (int i_ = 0; i_ < 4; ++i_) {                                     \
            a_[i_] = *(const bf16x8*)(AS_ + (wm * 64 + i_ * 16 + r) * 64 + co_); \
            b_[i_] = *(const bf16x8*)(BS_ + (wn * 64 + i_ * 16 + r) * 64 + co_); \
        }                                                                    \
        _Pragma("unroll")                                                    \
        for (int mi_ = 0; mi_ < 4; ++mi_)                                    \
            _Pragma("unroll")                                                \
            for (int ni_ = 0; ni_ < 4; ++ni_)                                \
                acc[mi_][ni_] = mfma16(a_[mi_], b_[ni_], acc[mi_][ni_]);     \
    }                                                                        \
    __builtin_amdgcn_s_setprio(0);

__global__ __launch_bounds__(256) void k_pv(
    const short* __restrict__ P, const short* __restrict__ VT,
    float* __restrict__ out)
{
    const int tid = threadIdx.x, wave = tid >> 6, lane = tid & 63;
    const int r = lane & 15, half = lane >> 4;
    const int wm = wave >> 1, wn = wave & 1;

    // XCD-chunked swizzle: 512 blocks, 8 XCDs, 64 blocks/XCD chunk. Blocks
    // sharing a P row-panel (consecutive w) land on one XCD's L2.
    const int bid = blockIdx.x;
    const int w = (bid & 7) * 64 + (bid >> 3);
    const int vx = w & 7;
    const int qy = (w >> 3) & 15;
    const int batch = w >> 7;
    const int qB = qy * 128;
    const int vB = vx * 128;
    const short* Pp = P + (size_t)batch * SS * SS;
    const short* Vp = VT + (size_t)batch * EE * SS;

    __shared__ short As0[128 * 64];
    __shared__ short Bs0[128 * 64];
    __shared__ short As1[128 * 64];
    __shared__ short Bs1[128 * 64];

    const int l8 = lane >> 3;
    const int cSrc = ((lane & 7) ^ l8) * 8;          // shorts, pre-swizzled src
    const short* aSrc = Pp + (size_t)(qB + wave * 8 + l8) * SS + cSrc;
    const short* bSrc = Vp + (size_t)(vB + wave * 8 + l8) * SS + cSrc;
    const int stDst = wave * 8 * 64;

    f32x4 acc[4][4] = {};
    const int sw = r & 7;

    PV_STAGE(As0, Bs0, 0)
    __syncthreads();
    for (int k0 = 0; k0 < SS; k0 += 128) {
        PV_STAGE(As1, Bs1, k0 + 64)          // prefetch odd tile
        PV_COMPUTE(As0, Bs0)
        __syncthreads();                     // drain: As1/Bs1 ready, As0 free
        if (k0 + 128 < SS) PV_STAGE(As0, Bs0, k0 + 128)  // prefetch even tile
        PV_COMPUTE(As1, Bs1)
        __syncthreads();
    }

    float* op = out + (size_t)batch * SS * EE;
    const int r4 = half * 4;
    #pragma unroll
    for (int mi = 0; mi < 4; ++mi)
        #pragma unroll
        for (int ni = 0; ni < 4; ++ni)
            #pragma unroll
            for (int ri = 0; ri < 4; ++ri)
                op[(size_t)(qB + wm * 64 + mi * 16 + r4 + ri) * EE + vB + wn * 64 + ni * 16 + r] = acc[mi][ni][ri];
}

// ---------------------------------------------------------------------------
extern "C" void kernel_launch(void* const* d_in, const int* in_sizes, int n_in,
                              void* d_out, int out_size, void* d_ws, size_t ws_size,
                              hipStream_t stream) {
    (void)in_sizes; (void)n_in; (void)out_size; (void)ws_size;
    const float* x   = (const float*)d_in[0];
    const float* y   = (const float*)d_in[1];
    const float* Wq  = (const float*)d_in[2];
    const float* bq  = (const float*)d_in[3];
    const float* Wk  = (const float*)d_in[4];
    const float* bk  = (const float*)d_in[5];
    const float* WvR = (const float*)d_in[6];
    const float* bvR = (const float*)d_in[7];
    const float* WvL = (const float*)d_in[8];
    const float* bvL = (const float*)d_in[9];
    float* out = (float*)d_out;

    short* Qb  = (short*)d_ws;
    short* Kb  = Qb  + (size_t)MTOT * DD;
    short* VRb = Kb  + (size_t)MTOT * DD;
    short* VT  = VRb + (size_t)MTOT * DD;
    short* Pb  = VT  + (size_t)NB * EE * SS;
    short* Wqb = Pb  + (size_t)NB * SS * SS;
    short* Wkb = Wqb + (size_t)DD * EE;
    short* Wvb = Wkb + (size_t)DD * EE;

    k_prep<<<dim3(DD * EE / 1024), 256, 0, stream>>>(Wq, Wk, WvR, Wqb, Wkb, Wvb);
    k_proj<<<dim3(MTOT / 16, 2), 256, 0, stream>>>(x, y, Wqb, Wkb, Wvb, bq, bk, bvR, Qb, Kb, VRb);
    k_vproj<<<dim3(EE / 64, MTOT / 64), 256, 0, stream>>>(WvL, bvL, VRb, VT);
    k_softmax<<<dim3(SS / 16, NB), 512, 0, stream>>>(Qb, Kb, Pb);
    k_pv<<<dim3(512), 256, 0, stream>>>(Pb, VT, out);
}

// Round 7
// 108.136 us; speedup vs baseline: 2.5934x; 1.1722x over previous
//
#include <hip/hip_runtime.h>
#include <hip/hip_bf16.h>

#define DEV static __device__ __forceinline__
#define AS1 __attribute__((address_space(1)))
#define AS3 __attribute__((address_space(3)))

typedef __attribute__((ext_vector_type(8))) short bf16x8;
typedef __attribute__((ext_vector_type(4))) short bf16x4;
typedef __attribute__((ext_vector_type(4))) float f32x4;

constexpr int NB = 4;        // batches
constexpr int SS = 2048;     // seq
constexpr int EE = 1024;     // embed
constexpr int DD = 64;       // low-rank d
constexpr int MTOT = NB * SS;  // 8192 rows total

// Q is pre-scaled by 1/sqrt(D) * log2(e) so softmax runs in exp2 domain.
#define QSCALE (0.125f * 1.44269504088896340736f)

DEV short f2bf(float f) {
    union { float f; unsigned u; } v; v.f = f;
    unsigned u = v.u;
    u += 0x7FFFu + ((u >> 16) & 1u);   // RNE
    return (short)(u >> 16);
}

DEV bf16x8 load8(const float* p, float s) {   // p must be 16B aligned
    float4 u = *(const float4*)(p);
    float4 v = *(const float4*)(p + 4);
    bf16x8 r;
    r[0] = f2bf(u.x * s); r[1] = f2bf(u.y * s); r[2] = f2bf(u.z * s); r[3] = f2bf(u.w * s);
    r[4] = f2bf(v.x * s); r[5] = f2bf(v.y * s); r[6] = f2bf(v.z * s); r[7] = f2bf(v.w * s);
    return r;
}

DEV f32x4 mfma16(bf16x8 a, bf16x8 b, f32x4 c) {
    return __builtin_amdgcn_mfma_f32_16x16x32_bf16(a, b, c, 0, 0, 0);
}

DEV float redmax16(float v) {
    v = fmaxf(v, __shfl_xor(v, 1)); v = fmaxf(v, __shfl_xor(v, 2));
    v = fmaxf(v, __shfl_xor(v, 4)); v = fmaxf(v, __shfl_xor(v, 8));
    return v;
}
DEV float redsum16(float v) {
    v += __shfl_xor(v, 1); v += __shfl_xor(v, 2);
    v += __shfl_xor(v, 4); v += __shfl_xor(v, 8);
    return v;
}

// ---------------------------------------------------------------------------
// K0 v2: pre-convert W to bf16 in MFMA-FRAGMENT order (Wq scaled by QSCALE).
// W'[((kq4*8+it)*4+n)*64 + lane] (16B chunks): chunk = W[n*16+(lane&15)]
// [kq4*256+it*32+(lane>>4)*8 .. +8]. A k_proj wave then loads one contiguous
// 1KB per (it,n) — kills the 16-row-scatter (64B-sector amplification).
// 24576 chunks total (3 matrices); grid 96, block 256.
// ---------------------------------------------------------------------------
__global__ __launch_bounds__(256) void k_prep(
    const float* __restrict__ Wq, const float* __restrict__ Wk,
    const float* __restrict__ Wv,
    short* __restrict__ Wqb, short* __restrict__ Wkb, short* __restrict__ Wvb)
{
    int g = blockIdx.x * 256 + threadIdx.x;      // 0..24575
    int mat = g >> 13;                           // 0,1,2
    int c = g & 8191;                            // chunk within matrix
    int lane = c & 63;
    int fn = (c >> 6) & 3;                       // n
    int it = (c >> 8) & 7;
    int kq4 = c >> 11;                           // 0..3 (K-quarter = wave)
    int r = lane & 15, half = lane >> 4;
    int row = fn * 16 + r;
    int col = kq4 * 256 + it * 32 + half * 8;
    const float* W = (mat == 0) ? Wq : ((mat == 1) ? Wk : Wv);
    short* O = (mat == 0) ? Wqb : ((mat == 1) ? Wkb : Wvb);
    float s = (mat == 0) ? QSCALE : 1.0f;
    bf16x8 o = load8(W + (size_t)row * EE + col, s);
    *(bf16x8*)(O + (size_t)c * 8) = o;
}

// ---------------------------------------------------------------------------
// K1 v4: projections, split-K, frag-ordered W + A-prefetch-all.
// Block = 16 rows; 4 waves each own a K-quarter (256); LDS reduce.
// blockIdx.y==0: Q from x; ==1: K and VR from y. grid (512, 2), block 256.
// ---------------------------------------------------------------------------
__global__ __launch_bounds__(256) void k_proj(
    const float* __restrict__ x, const float* __restrict__ y,
    const short* __restrict__ Wqb, const short* __restrict__ Wkb,
    const short* __restrict__ Wvb,
    const float* __restrict__ bq, const float* __restrict__ bk,
    const float* __restrict__ bv,
    short* __restrict__ Qb, short* __restrict__ Kb, short* __restrict__ VRb)
{
    const int tid = threadIdx.x, wave = tid >> 6, lane = tid & 63;
    const int r = lane & 15, half = lane >> 4;
    const int rb = blockIdx.x * 16;
    const bool isQ = (blockIdx.y == 0);
    const float* src = isQ ? x : y;
    const short* wA = isQ ? Wqb : Wkb;
    const int kq = wave * 256;

    __shared__ f32x4 red[4][8][64];

    f32x4 accA[4] = {}, accB[4] = {};
    const float* arow = src + (size_t)(rb + r) * EE + kq + half * 8;
    const short* wbase = wA + (size_t)wave * 16384 + lane * 8;   // frag-ordered
    const short* vbase = Wvb + (size_t)wave * 16384 + lane * 8;

    // issue ALL 16 A-loads up front — Little's-law fix
    float4 af0[8], af1[8];
    #pragma unroll
    for (int it = 0; it < 8; ++it) {
        af0[it] = *(const float4*)(arow + it * 32);
        af1[it] = *(const float4*)(arow + it * 32 + 4);
    }

    #pragma unroll
    for (int it = 0; it < 8; ++it) {
        bf16x8 a;
        a[0] = f2bf(af0[it].x); a[1] = f2bf(af0[it].y);
        a[2] = f2bf(af0[it].z); a[3] = f2bf(af0[it].w);
        a[4] = f2bf(af1[it].x); a[5] = f2bf(af1[it].y);
        a[6] = f2bf(af1[it].z); a[7] = f2bf(af1[it].w);
        #pragma unroll
        for (int n = 0; n < 4; ++n) {
            bf16x8 b = *(const bf16x8*)(wbase + (it * 4 + n) * 64 * 8);
            accA[n] = mfma16(a, b, accA[n]);
        }
        if (!isQ) {
            #pragma unroll
            for (int n = 0; n < 4; ++n) {
                bf16x8 b = *(const bf16x8*)(vbase + (it * 4 + n) * 64 * 8);
                accB[n] = mfma16(a, b, accB[n]);
            }
        }
    }

    #pragma unroll
    for (int n = 0; n < 4; ++n) red[wave][n][lane] = accA[n];
    if (!isQ) {
        #pragma unroll
        for (int n = 0; n < 4; ++n) red[wave][4 + n][lane] = accB[n];
    }
    __syncthreads();

    const int n = wave;
    const int col = n * 16 + r;
    f32x4 s = red[0][n][lane];
    #pragma unroll
    for (int w = 1; w < 4; ++w) s += red[w][n][lane];
    float biasA = isQ ? (bq[col] * QSCALE) : bk[col];
    short* dstA = isQ ? Qb : Kb;
    #pragma unroll
    for (int ri = 0; ri < 4; ++ri)
        dstA[(size_t)(rb + half * 4 + ri) * DD + col] = f2bf(s[ri] + biasA);
    if (!isQ) {
        f32x4 t = red[0][4 + n][lane];
        #pragma unroll
        for (int w = 1; w < 4; ++w) t += red[w][4 + n][lane];
        float biasB = bv[col];
        #pragma unroll
        for (int ri = 0; ri < 4; ++ri)
            VRb[(size_t)(rb + half * 4 + ri) * DD + col] = f2bf(t[ri] + biasB);
    }
}

// ---------------------------------------------------------------------------
// K2: V^T[v][s] = sum_d WvL[v][d]*VR[s][d] + bvL[v], bf16 transposed per
// batch. grid (E/64, 8192/64), block 256.
// ---------------------------------------------------------------------------
__global__ __launch_bounds__(256) void k_vproj(
    const float* __restrict__ WvL, const float* __restrict__ bvL,
    const short* __restrict__ VRb, short* __restrict__ VT)
{
    const int tid = threadIdx.x, wave = tid >> 6, lane = tid & 63;
    const int r = lane & 15, half = lane >> 4;
    const int vb = blockIdx.x * 64;
    const int sb = blockIdx.y * 64;
    const int batch = sb >> 11, s_l = sb & (SS - 1);

    __shared__ float lds[64][68];

    f32x4 acc[4] = {};
    #pragma unroll
    for (int kk = 0; kk < 2; ++kk) {
        bf16x8 b = *(const bf16x8*)(VRb + (size_t)(sb + wave * 16 + r) * DD + kk * 32 + half * 8);
        #pragma unroll
        for (int m = 0; m < 4; ++m) {
            bf16x8 a = load8(WvL + (size_t)(vb + m * 16 + r) * DD + kk * 32 + half * 8, 1.0f);
            acc[m] = mfma16(a, b, acc[m]);
        }
    }
    const int r4 = half * 4;
    #pragma unroll
    for (int m = 0; m < 4; ++m)
        #pragma unroll
        for (int ri = 0; ri < 4; ++ri)
            lds[m * 16 + r4 + ri][wave * 16 + r] = acc[m][ri];
    __syncthreads();
    int v = tid >> 2, q4 = (tid & 3) * 16;
    float bias = bvL[vb + v];
    short* dst = VT + (size_t)batch * EE * SS + (size_t)(vb + v) * SS + s_l + q4;
    bf16x8 o0, o1;
    #pragma unroll
    for (int j = 0; j < 8; ++j) o0[j] = f2bf(lds[v][q4 + j] + bias);
    #pragma unroll
    for (int j = 0; j < 8; ++j) o1[j] = f2bf(lds[v][q4 + 8 + j] + bias);
    *(bf16x8*)dst = o0;
    *(bf16x8*)(dst + 8) = o1;
}

// ---------------------------------------------------------------------------
// K3 v5: column softmax, swapped MFMA + per-wave LDS-staged Q tiles.
// Each 16x64 Q-tile (contiguous 2KB) is staged via global_load_lds with
// both-sides XOR swizzle (conflict-spread ds_read_b128), double-buffered
// per wave with counted vmcnt — no block barriers in the loop.
// Block = 16 k-cols; 8 waves x 256 q-rows. grid (S/16, NB), block 512.
// ---------------------------------------------------------------------------
#define SM_STAGE(buf, t) {                                                        \
    const short* s0_ = Qp + (size_t)(q0 + (t) * 16 + sr) * DD + scol;             \
    const short* s1_ = Qp + (size_t)(q0 + (t) * 16 + 8 + sr) * DD + scol;         \
    __builtin_amdgcn_global_load_lds((const AS1 void*)s0_,                        \
        (AS3 void*)(&qs[wave][buf][0][0]), 16, 0, 0);                             \
    __builtin_amdgcn_global_load_lds((const AS1 void*)s1_,                        \
        (AS3 void*)(&qs[wave][buf][8][0]), 16, 0, 0); }

#define SM_QKT(buf, t) {                                                          \
    bf16x8 a0 = *(const bf16x8*)(&qs[wave][buf][r][(half ^ rs) * 8]);             \
    bf16x8 a1 = *(const bf16x8*)(&qs[wave][buf][r][((half + 4) ^ rs) * 8]);       \
    f32x4 c = {};                                                                 \
    c = mfma16(kf0, a0, c);                                                       \
    c = mfma16(kf1, a1, c);                                                       \
    s[t] = c; }

__global__ __launch_bounds__(512) void k_softmax(
    const short* __restrict__ Qb, const short* __restrict__ Kb,
    short* __restrict__ P)
{
    const int tid = threadIdx.x, wave = tid >> 6, lane = tid & 63;
    const int r = lane & 15, half = lane >> 4;
    const int batch = blockIdx.y;
    const int kb = blockIdx.x * 16;
    const short* Qp = Qb + (size_t)batch * SS * DD;
    const short* Kp = Kb + (size_t)batch * SS * DD;
    short* Pp = P + (size_t)batch * SS * SS;

    __shared__ short qs[8][2][16][64];     // per-wave double-buffered Q tile
    __shared__ float smax[8][16], ssum[8][16];

    // A-operand = K rows (16 k), contiguous d (one-time scattered load, tiny)
    bf16x8 kf0 = *(const bf16x8*)(Kp + (size_t)(kb + r) * DD + half * 8);
    bf16x8 kf1 = *(const bf16x8*)(Kp + (size_t)(kb + r) * DD + 32 + half * 8);

    const int q0 = wave * 256;
    // staging lane map: row sr (+8 for call1), swizzled col chunk
    const int sr = lane >> 3;
    const int scol = ((lane & 7) ^ sr) * 8;
    const int rs = r & 7;                  // read-side XOR

    f32x4 s[16];
    SM_STAGE(0, 0)
    #pragma unroll
    for (int t = 0; t < 16; t += 2) {
        SM_STAGE(1, t + 1)
        asm volatile("s_waitcnt vmcnt(2)" ::: "memory");   // tile t landed
        SM_QKT(0, t)
        if (t + 2 < 16) {
            SM_STAGE(0, t + 2)
            asm volatile("s_waitcnt vmcnt(2)" ::: "memory"); // tile t+1 landed
        } else {
            asm volatile("s_waitcnt vmcnt(0)" ::: "memory");
        }
        SM_QKT(1, t + 1)
    }

    // per-lane max over its 16 q-values, per k-component
    f32x4 m4 = s[0];
    #pragma unroll
    for (int t = 1; t < 16; ++t) {
        #pragma unroll
        for (int ri = 0; ri < 4; ++ri) m4[ri] = fmaxf(m4[ri], s[t][ri]);
    }
    #pragma unroll
    for (int ri = 0; ri < 4; ++ri) m4[ri] = redmax16(m4[ri]);
    if (r == 0) {
        #pragma unroll
        for (int ri = 0; ri < 4; ++ri) smax[wave][half * 4 + ri] = m4[ri];
    }
    __syncthreads();
    f32x4 M;
    #pragma unroll
    for (int ri = 0; ri < 4; ++ri) {
        float v = smax[0][half * 4 + ri];
        #pragma unroll
        for (int w = 1; w < 8; ++w) v = fmaxf(v, smax[w][half * 4 + ri]);
        M[ri] = v;
    }

    f32x4 l4 = {};
    #pragma unroll
    for (int t = 0; t < 16; ++t) {
        #pragma unroll
        for (int ri = 0; ri < 4; ++ri) {
            s[t][ri] = exp2f(s[t][ri] - M[ri]);
            l4[ri] += s[t][ri];
        }
    }
    #pragma unroll
    for (int ri = 0; ri < 4; ++ri) l4[ri] = redsum16(l4[ri]);
    if (r == 0) {
        #pragma unroll
        for (int ri = 0; ri < 4; ++ri) ssum[wave][half * 4 + ri] = l4[ri];
    }
    __syncthreads();
    f32x4 rl;
    #pragma unroll
    for (int ri = 0; ri < 4; ++ri) {
        float v = 0.f;
        #pragma unroll
        for (int w = 0; w < 8; ++w) v += ssum[w][half * 4 + ri];
        rl[ri] = 1.0f / v;
    }

    #pragma unroll
    for (int t = 0; t < 16; ++t) {
        bf16x4 o;
        #pragma unroll
        for (int ri = 0; ri < 4; ++ri) o[ri] = f2bf(s[t][ri] * rl[ri]);
        *(bf16x4*)(Pp + (size_t)(q0 + t * 16 + r) * SS + kb + half * 4) = o;
    }
}

// ---------------------------------------------------------------------------
// K4: out[q][v] = sum_k P[q][k] * VT[v][k]. 128x128 tile, BK=64, statically
// double-buffered LDS, prefetch-before-compute, XOR both-sides swizzle,
// XCD-chunked swizzle, setprio around MFMA. grid 512 (flat), block 256.
// ---------------------------------------------------------------------------
#define PV_STAGE(AD, BD, k0)                                                 \
    _Pragma("unroll")                                                        \
    for (int i_ = 0; i_ < 4; ++i_) {                                         \
        __builtin_amdgcn_global_load_lds(                                    \
            (const AS1 void*)(aSrc + (size_t)i_ * 32 * SS + (k0)),           \
            (AS3 void*)(AD + stDst + i_ * 32 * 64), 16, 0, 0);               \
        __builtin_amdgcn_global_load_lds(                                    \
            (const AS1 void*)(bSrc + (size_t)i_ * 32 * SS + (k0)),           \
            (AS3 void*)(BD + stDst + i_ * 32 * 64), 16, 0, 0);               \
    }

#define PV_COMPUTE(AS_, BS_)                                                 \
    __builtin_amdgcn_s_setprio(1);                                           \
    _Pragma("unroll")                                                        \
    for (int kk_ = 0; kk_ < 2; ++kk_) {                                      \
        const int co_ = ((kk_ * 4 + half) ^ sw) * 8;                         \
        bf16x8 a_[4], b_[4];                                                 \
        _Pragma("unroll")                                                    \
        for (int i_ = 0; i_ < 4; ++i_) {                                     \
            a_[i_] = *(const bf16x8*)(AS_ + (wm * 64 + i_ * 16 + r) * 64 + co_); \
            b_[i_] = *(const bf16x8*)(BS_ + (wn * 64 + i_ * 16 + r) * 64 + co_); \
        }                                                                    \
        _Pragma("unroll")                                                    \
        for (int mi_ = 0; mi_ < 4; ++mi_)                                    \
            _Pragma("unroll")                                                \
            for (int ni_ = 0; ni_ < 4; ++ni_)                                \
                acc[mi_][ni_] = mfma16(a_[mi_], b_[ni_], acc[mi_][ni_]);     \
    }                                                                        \
    __builtin_amdgcn_s_setprio(0);

__global__ __launch_bounds__(256) void k_pv(
    const short* __restrict__ P, const short* __restrict__ VT,
    float* __restrict__ out)
{
    const int tid = threadIdx.x, wave = tid >> 6, lane = tid & 63;
    const int r = lane & 15, half = lane >> 4;
    const int wm = wave >> 1, wn = wave & 1;

    const int bid = blockIdx.x;
    const int w = (bid & 7) * 64 + (bid >> 3);
    const int vx = w & 7;
    const int qy = (w >> 3) & 15;
    const int batch = w >> 7;
    const int qB = qy * 128;
    const int vB = vx * 128;
    const short* Pp = P + (size_t)batch * SS * SS;
    const short* Vp = VT + (size_t)batch * EE * SS;

    __shared__ short As0[128 * 64];
    __shared__ short Bs0[128 * 64];
    __shared__ short As1[128 * 64];
    __shared__ short Bs1[128 * 64];

    const int l8 = lane >> 3;
    const int cSrc = ((lane & 7) ^ l8) * 8;          // shorts, pre-swizzled src
    const short* aSrc = Pp + (size_t)(qB + wave * 8 + l8) * SS + cSrc;
    const short* bSrc = Vp + (size_t)(vB + wave * 8 + l8) * SS + cSrc;
    const int stDst = wave * 8 * 64;

    f32x4 acc[4][4] = {};
    const int sw = r & 7;

    PV_STAGE(As0, Bs0, 0)
    __syncthreads();
    for (int k0 = 0; k0 < SS; k0 += 128) {
        PV_STAGE(As1, Bs1, k0 + 64)          // prefetch odd tile
        PV_COMPUTE(As0, Bs0)
        __syncthreads();                     // drain: As1/Bs1 ready, As0 free
        if (k0 + 128 < SS) PV_STAGE(As0, Bs0, k0 + 128)  // prefetch even tile
        PV_COMPUTE(As1, Bs1)
        __syncthreads();
    }

    float* op = out + (size_t)batch * SS * EE;
    const int r4 = half * 4;
    #pragma unroll
    for (int mi = 0; mi < 4; ++mi)
        #pragma unroll
        for (int ni = 0; ni < 4; ++ni)
            #pragma unroll
            for (int ri = 0; ri < 4; ++ri)
                op[(size_t)(qB + wm * 64 + mi * 16 + r4 + ri) * EE + vB + wn * 64 + ni * 16 + r] = acc[mi][ni][ri];
}

// ---------------------------------------------------------------------------
extern "C" void kernel_launch(void* const* d_in, const int* in_sizes, int n_in,
                              void* d_out, int out_size, void* d_ws, size_t ws_size,
                              hipStream_t stream) {
    (void)in_sizes; (void)n_in; (void)out_size; (void)ws_size;
    const float* x   = (const float*)d_in[0];
    const float* y   = (const float*)d_in[1];
    const float* Wq  = (const float*)d_in[2];
    const float* bq  = (const float*)d_in[3];
    const float* Wk  = (const float*)d_in[4];
    const float* bk  = (const float*)d_in[5];
    const float* WvR = (const float*)d_in[6];
    const float* bvR = (const float*)d_in[7];
    const float* WvL = (const float*)d_in[8];
    const float* bvL = (const float*)d_in[9];
    float* out = (float*)d_out;

    short* Qb  = (short*)d_ws;
    short* Kb  = Qb  + (size_t)MTOT * DD;
    short* VRb = Kb  + (size_t)MTOT * DD;
    short* VT  = VRb + (size_t)MTOT * DD;
    short* Pb  = VT  + (size_t)NB * EE * SS;
    short* Wqb = Pb  + (size_t)NB * SS * SS;
    short* Wkb = Wqb + (size_t)DD * EE;
    short* Wvb = Wkb + (size_t)DD * EE;

    k_prep<<<dim3(96), 256, 0, stream>>>(Wq, Wk, WvR, Wqb, Wkb, Wvb);
    k_proj<<<dim3(MTOT / 16, 2), 256, 0, stream>>>(x, y, Wqb, Wkb, Wvb, bq, bk, bvR, Qb, Kb, VRb);
    k_vproj<<<dim3(EE / 64, MTOT / 64), 256, 0, stream>>>(WvL, bvL, VRb, VT);
    k_softmax<<<dim3(SS / 16, NB), 512, 0, stream>>>(Qb, Kb, Pb);
    k_pv<<<dim3(512), 256, 0, stream>>>(Pb, VT, out);
}

// Round 8
// 80.019 us; speedup vs baseline: 3.5047x; 1.3514x over previous
//
#include <hip/hip_runtime.h>
#include <hip/hip_bf16.h>

#define DEV static __device__ __forceinline__
#define AS1 __attribute__((address_space(1)))
#define AS3 __attribute__((address_space(3)))

typedef __attribute__((ext_vector_type(8))) short bf16x8;
typedef __attribute__((ext_vector_type(4))) short bf16x4;
typedef __attribute__((ext_vector_type(4))) float f32x4;

constexpr int NB = 4;        // batches
constexpr int SS = 2048;     // seq
constexpr int EE = 1024;     // embed
constexpr int DD = 64;       // low-rank d
constexpr int MTOT = NB * SS;  // 8192 rows total
constexpr int D2 = 80;       // T width: 64 d + ones-col(64) + 15 pad
constexpr int K2 = 160;      // GEMM2 K: [Thi | Tlo]

// Q is pre-scaled by 1/sqrt(D) * log2(e) so softmax runs in exp2 domain.
#define QSCALE (0.125f * 1.44269504088896340736f)

DEV short f2bf(float f) {
    union { float f; unsigned u; } v; v.f = f;
    unsigned u = v.u;
    u += 0x7FFFu + ((u >> 16) & 1u);   // RNE
    return (short)(u >> 16);
}
DEV float bf2f(short h) {
    union { unsigned u; float f; } v; v.u = ((unsigned)(unsigned short)h) << 16;
    return v.f;
}

DEV bf16x8 load8(const float* p, float s) {   // p must be 16B aligned
    float4 u = *(const float4*)(p);
    float4 v = *(const float4*)(p + 4);
    bf16x8 r;
    r[0] = f2bf(u.x * s); r[1] = f2bf(u.y * s); r[2] = f2bf(u.z * s); r[3] = f2bf(u.w * s);
    r[4] = f2bf(v.x * s); r[5] = f2bf(v.y * s); r[6] = f2bf(v.z * s); r[7] = f2bf(v.w * s);
    return r;
}

DEV f32x4 mfma16(bf16x8 a, bf16x8 b, f32x4 c) {
    return __builtin_amdgcn_mfma_f32_16x16x32_bf16(a, b, c, 0, 0, 0);
}

DEV float redmax16(float v) {
    v = fmaxf(v, __shfl_xor(v, 1)); v = fmaxf(v, __shfl_xor(v, 2));
    v = fmaxf(v, __shfl_xor(v, 4)); v = fmaxf(v, __shfl_xor(v, 8));
    return v;
}
DEV float redsum16(float v) {
    v += __shfl_xor(v, 1); v += __shfl_xor(v, 2);
    v += __shfl_xor(v, 4); v += __shfl_xor(v, 8);
    return v;
}

// ---------------------------------------------------------------------------
// K0 v2: pre-convert W to bf16 in MFMA-FRAGMENT order (Wq scaled by QSCALE).
// ---------------------------------------------------------------------------
__global__ __launch_bounds__(256) void k_prep(
    const float* __restrict__ Wq, const float* __restrict__ Wk,
    const float* __restrict__ Wv,
    short* __restrict__ Wqb, short* __restrict__ Wkb, short* __restrict__ Wvb)
{
    int g = blockIdx.x * 256 + threadIdx.x;      // 0..24575
    int mat = g >> 13;                           // 0,1,2
    int c = g & 8191;                            // chunk within matrix
    int lane = c & 63;
    int fn = (c >> 6) & 3;                       // n
    int it = (c >> 8) & 7;
    int kq4 = c >> 11;                           // 0..3 (K-quarter = wave)
    int r = lane & 15, half = lane >> 4;
    int row = fn * 16 + r;
    int col = kq4 * 256 + it * 32 + half * 8;
    const float* W = (mat == 0) ? Wq : ((mat == 1) ? Wk : Wv);
    short* O = (mat == 0) ? Wqb : ((mat == 1) ? Wkb : Wvb);
    float s = (mat == 0) ? QSCALE : 1.0f;
    bf16x8 o = load8(W + (size_t)row * EE + col, s);
    *(bf16x8*)(O + (size_t)c * 8) = o;
}

// ---------------------------------------------------------------------------
// K0b: build Wcat [1024][160] bf16: cols 0-63 = WvL[v][d], col 64 = bvL[v],
// 65-79 = 0; cols 80-159 = same again (Tlo uses the same bf16 W).
// grid 80, block 256 (8 cols/thread).
// ---------------------------------------------------------------------------
__global__ __launch_bounds__(256) void k_wprep(
    const float* __restrict__ WvL, const float* __restrict__ bvL,
    short* __restrict__ Wcat)
{
    int g = blockIdx.x * 256 + threadIdx.x;      // 0..20479
    int v = g / 20;
    int c = (g % 20) * 8;
    bf16x8 o;
    #pragma unroll
    for (int j = 0; j < 8; ++j) {
        int jj = c + j;
        int d = (jj < D2) ? jj : (jj - D2);
        float val = (d < 64) ? WvL[(size_t)v * DD + d] : ((d == 64) ? bvL[v] : 0.f);
        o[j] = f2bf(val);
    }
    *(bf16x8*)(Wcat + (size_t)v * K2 + c) = o;
}

// ---------------------------------------------------------------------------
// K1 v4: projections, split-K, frag-ordered W + A-prefetch-all.
// grid (512, 2), block 256.
// ---------------------------------------------------------------------------
__global__ __launch_bounds__(256) void k_proj(
    const float* __restrict__ x, const float* __restrict__ y,
    const short* __restrict__ Wqb, const short* __restrict__ Wkb,
    const short* __restrict__ Wvb,
    const float* __restrict__ bq, const float* __restrict__ bk,
    const float* __restrict__ bv,
    short* __restrict__ Qb, short* __restrict__ Kb, short* __restrict__ VRb)
{
    const int tid = threadIdx.x, wave = tid >> 6, lane = tid & 63;
    const int r = lane & 15, half = lane >> 4;
    const int rb = blockIdx.x * 16;
    const bool isQ = (blockIdx.y == 0);
    const float* src = isQ ? x : y;
    const short* wA = isQ ? Wqb : Wkb;
    const int kq = wave * 256;

    __shared__ f32x4 red[4][8][64];

    f32x4 accA[4] = {}, accB[4] = {};
    const float* arow = src + (size_t)(rb + r) * EE + kq + half * 8;
    const short* wbase = wA + (size_t)wave * 16384 + lane * 8;   // frag-ordered
    const short* vbase = Wvb + (size_t)wave * 16384 + lane * 8;

    // issue ALL 16 A-loads up front — Little's-law fix
    float4 af0[8], af1[8];
    #pragma unroll
    for (int it = 0; it < 8; ++it) {
        af0[it] = *(const float4*)(arow + it * 32);
        af1[it] = *(const float4*)(arow + it * 32 + 4);
    }

    #pragma unroll
    for (int it = 0; it < 8; ++it) {
        bf16x8 a;
        a[0] = f2bf(af0[it].x); a[1] = f2bf(af0[it].y);
        a[2] = f2bf(af0[it].z); a[3] = f2bf(af0[it].w);
        a[4] = f2bf(af1[it].x); a[5] = f2bf(af1[it].y);
        a[6] = f2bf(af1[it].z); a[7] = f2bf(af1[it].w);
        #pragma unroll
        for (int n = 0; n < 4; ++n) {
            bf16x8 b = *(const bf16x8*)(wbase + (it * 4 + n) * 64 * 8);
            accA[n] = mfma16(a, b, accA[n]);
        }
        if (!isQ) {
            #pragma unroll
            for (int n = 0; n < 4; ++n) {
                bf16x8 b = *(const bf16x8*)(vbase + (it * 4 + n) * 64 * 8);
                accB[n] = mfma16(a, b, accB[n]);
            }
        }
    }

    #pragma unroll
    for (int n = 0; n < 4; ++n) red[wave][n][lane] = accA[n];
    if (!isQ) {
        #pragma unroll
        for (int n = 0; n < 4; ++n) red[wave][4 + n][lane] = accB[n];
    }
    __syncthreads();

    const int n = wave;
    const int col = n * 16 + r;
    f32x4 s = red[0][n][lane];
    #pragma unroll
    for (int w = 1; w < 4; ++w) s += red[w][n][lane];
    float biasA = isQ ? (bq[col] * QSCALE) : bk[col];
    short* dstA = isQ ? Qb : Kb;
    #pragma unroll
    for (int ri = 0; ri < 4; ++ri)
        dstA[(size_t)(rb + half * 4 + ri) * DD + col] = f2bf(s[ri] + biasA);
    if (!isQ) {
        f32x4 t = red[0][4 + n][lane];
        #pragma unroll
        for (int w = 1; w < 4; ++w) t += red[w][4 + n][lane];
        float biasB = bv[col];
        #pragma unroll
        for (int ri = 0; ri < 4; ++ri)
            VRb[(size_t)(rb + half * 4 + ri) * DD + col] = f2bf(t[ri] + biasB);
    }
}

// ---------------------------------------------------------------------------
// K2: transpose VRb [8192][64] -> VRbT [batch][64][2048] (bf16).
// grid 128, block 256 (64 s-rows per block).
// ---------------------------------------------------------------------------
__global__ __launch_bounds__(256) void k_tr(
    const short* __restrict__ VRb, short* __restrict__ VRbT)
{
    const int tid = threadIdx.x;
    const int sb = blockIdx.x * 64;
    const int batch = sb >> 11, s_l = sb & (SS - 1);
    __shared__ short t[64][72];

    #pragma unroll
    for (int i = 0; i < 2; ++i) {
        int row = i * 32 + (tid >> 3), col = (tid & 7) * 8;
        *(bf16x8*)&t[row][col] = *(const bf16x8*)(VRb + (size_t)(sb + row) * DD + col);
    }
    __syncthreads();
    int d = tid >> 2, c0 = (tid & 3) * 16;
    bf16x8 o0, o1;
    #pragma unroll
    for (int j = 0; j < 8; ++j) o0[j] = t[c0 + j][d];
    #pragma unroll
    for (int j = 0; j < 8; ++j) o1[j] = t[c0 + 8 + j][d];
    short* dst = VRbT + (size_t)batch * DD * SS + (size_t)d * SS + s_l + c0;
    *(bf16x8*)dst = o0;
    *(bf16x8*)(dst + 8) = o1;
}

// ---------------------------------------------------------------------------
// K3 v5: column softmax, swapped MFMA + per-wave LDS-staged Q tiles.
// grid (S/16, NB), block 512.
// ---------------------------------------------------------------------------
#define SM_STAGE(buf, t) {                                                        \
    const short* s0_ = Qp + (size_t)(q0 + (t) * 16 + sr) * DD + scol;             \
    const short* s1_ = Qp + (size_t)(q0 + (t) * 16 + 8 + sr) * DD + scol;         \
    __builtin_amdgcn_global_load_lds((const AS1 void*)s0_,                        \
        (AS3 void*)(&qs[wave][buf][0][0]), 16, 0, 0);                             \
    __builtin_amdgcn_global_load_lds((const AS1 void*)s1_,                        \
        (AS3 void*)(&qs[wave][buf][8][0]), 16, 0, 0); }

#define SM_QKT(buf, t) {                                                          \
    bf16x8 a0 = *(const bf16x8*)(&qs[wave][buf][r][(half ^ rs) * 8]);             \
    bf16x8 a1 = *(const bf16x8*)(&qs[wave][buf][r][((half + 4) ^ rs) * 8]);       \
    f32x4 c = {};                                                                 \
    c = mfma16(kf0, a0, c);                                                       \
    c = mfma16(kf1, a1, c);                                                       \
    s[t] = c; }

__global__ __launch_bounds__(512) void k_softmax(
    const short* __restrict__ Qb, const short* __restrict__ Kb,
    short* __restrict__ P)
{
    const int tid = threadIdx.x, wave = tid >> 6, lane = tid & 63;
    const int r = lane & 15, half = lane >> 4;
    const int batch = blockIdx.y;
    const int kb = blockIdx.x * 16;
    const short* Qp = Qb + (size_t)batch * SS * DD;
    const short* Kp = Kb + (size_t)batch * SS * DD;
    short* Pp = P + (size_t)batch * SS * SS;

    __shared__ short qs[8][2][16][64];     // per-wave double-buffered Q tile
    __shared__ float smax[8][16], ssum[8][16];

    bf16x8 kf0 = *(const bf16x8*)(Kp + (size_t)(kb + r) * DD + half * 8);
    bf16x8 kf1 = *(const bf16x8*)(Kp + (size_t)(kb + r) * DD + 32 + half * 8);

    const int q0 = wave * 256;
    const int sr = lane >> 3;
    const int scol = ((lane & 7) ^ sr) * 8;
    const int rs = r & 7;                  // read-side XOR

    f32x4 s[16];
    SM_STAGE(0, 0)
    #pragma unroll
    for (int t = 0; t < 16; t += 2) {
        SM_STAGE(1, t + 1)
        asm volatile("s_waitcnt vmcnt(2)" ::: "memory");   // tile t landed
        SM_QKT(0, t)
        if (t + 2 < 16) {
            SM_STAGE(0, t + 2)
            asm volatile("s_waitcnt vmcnt(2)" ::: "memory"); // tile t+1 landed
        } else {
            asm volatile("s_waitcnt vmcnt(0)" ::: "memory");
        }
        SM_QKT(1, t + 1)
    }

    f32x4 m4 = s[0];
    #pragma unroll
    for (int t = 1; t < 16; ++t) {
        #pragma unroll
        for (int ri = 0; ri < 4; ++ri) m4[ri] = fmaxf(m4[ri], s[t][ri]);
    }
    #pragma unroll
    for (int ri = 0; ri < 4; ++ri) m4[ri] = redmax16(m4[ri]);
    if (r == 0) {
        #pragma unroll
        for (int ri = 0; ri < 4; ++ri) smax[wave][half * 4 + ri] = m4[ri];
    }
    __syncthreads();
    f32x4 M;
    #pragma unroll
    for (int ri = 0; ri < 4; ++ri) {
        float v = smax[0][half * 4 + ri];
        #pragma unroll
        for (int w = 1; w < 8; ++w) v = fmaxf(v, smax[w][half * 4 + ri]);
        M[ri] = v;
    }

    f32x4 l4 = {};
    #pragma unroll
    for (int t = 0; t < 16; ++t) {
        #pragma unroll
        for (int ri = 0; ri < 4; ++ri) {
            s[t][ri] = exp2f(s[t][ri] - M[ri]);
            l4[ri] += s[t][ri];
        }
    }
    #pragma unroll
    for (int ri = 0; ri < 4; ++ri) l4[ri] = redsum16(l4[ri]);
    if (r == 0) {
        #pragma unroll
        for (int ri = 0; ri < 4; ++ri) ssum[wave][half * 4 + ri] = l4[ri];
    }
    __syncthreads();
    f32x4 rl;
    #pragma unroll
    for (int ri = 0; ri < 4; ++ri) {
        float v = 0.f;
        #pragma unroll
        for (int w = 0; w < 8; ++w) v += ssum[w][half * 4 + ri];
        rl[ri] = 1.0f / v;
    }

    #pragma unroll
    for (int t = 0; t < 16; ++t) {
        bf16x4 o;
        #pragma unroll
        for (int ri = 0; ri < 4; ++ri) o[ri] = f2bf(s[t][ri] * rl[ri]);
        *(bf16x4*)(Pp + (size_t)(q0 + t * 16 + r) * SS + kb + half * 4) = o;
    }
}

// ---------------------------------------------------------------------------
// K4: GEMM1 — Tpart[kch][q][0:80] = P[q][kslice] @ [VRbT^T | ones].
// Low-rank contraction: K=512 per block (split-K 4), BM=128, N=80 (5 frags;
// frag 4 is a constant ones-column -> rowsum R). Staging structure = proven
// k_pv pattern (gload_lds + XOR both-sides swizzle + static dbuf + setprio).
// grid 256 flat, block 256.
// ---------------------------------------------------------------------------
#define G1_STAGE(AD, BD, kc)                                                 \
    _Pragma("unroll")                                                        \
    for (int i_ = 0; i_ < 4; ++i_)                                           \
        __builtin_amdgcn_global_load_lds(                                    \
            (const AS1 void*)(aSrc + (size_t)i_ * 32 * SS + (kc)),           \
            (AS3 void*)(AD + stDst + i_ * 32 * 64), 16, 0, 0);               \
    _Pragma("unroll")                                                        \
    for (int i_ = 0; i_ < 2; ++i_)                                           \
        __builtin_amdgcn_global_load_lds(                                    \
            (const AS1 void*)(bSrc + (size_t)i_ * 32 * SS + (kc)),           \
            (AS3 void*)(BD + stDst + i_ * 32 * 64), 16, 0, 0);

#define G1_COMPUTE(AS_, BS_)                                                 \
    __builtin_amdgcn_s_setprio(1);                                           \
    _Pragma("unroll")                                                        \
    for (int kk_ = 0; kk_ < 2; ++kk_) {                                      \
        const int co_ = ((kk_ * 4 + half) ^ sw) * 8;                         \
        bf16x8 a_[2], b_[4];                                                 \
        a_[0] = *(const bf16x8*)(AS_ + (qw + r) * 64 + co_);                 \
        a_[1] = *(const bf16x8*)(AS_ + (qw + 16 + r) * 64 + co_);            \
        _Pragma("unroll")                                                    \
        for (int ni_ = 0; ni_ < 4; ++ni_)                                    \
            b_[ni_] = *(const bf16x8*)(BS_ + (ni_ * 16 + r) * 64 + co_);     \
        _Pragma("unroll")                                                    \
        for (int mi_ = 0; mi_ < 2; ++mi_) {                                  \
            _Pragma("unroll")                                                \
            for (int ni_ = 0; ni_ < 4; ++ni_)                                \
                acc[mi_][ni_] = mfma16(a_[mi_], b_[ni_], acc[mi_][ni_]);     \
            acc[mi_][4] = mfma16(a_[mi_], bOnes, acc[mi_][4]);               \
        }                                                                    \
    }                                                                        \
    __builtin_amdgcn_s_setprio(0);

__global__ __launch_bounds__(256) void k_gemm1(
    const short* __restrict__ P, const short* __restrict__ VRbT,
    float* __restrict__ Tpart)
{
    const int tid = threadIdx.x, wave = tid >> 6, lane = tid & 63;
    const int r = lane & 15, half = lane >> 4;
    const int mtile = blockIdx.x >> 2;           // 0..63 (128 q-rows each)
    const int kch = blockIdx.x & 3;              // split-K chunk (512)
    const int batch = mtile >> 4;
    const int qloc = (mtile & 15) * 128;
    const int kb = kch * 512;
    const short* Pp = P + (size_t)batch * SS * SS;
    const short* Vt = VRbT + (size_t)batch * DD * SS;

    __shared__ short As0[128 * 64];
    __shared__ short Bs0[64 * 64];
    __shared__ short As1[128 * 64];
    __shared__ short Bs1[64 * 64];

    const int l8 = lane >> 3;
    const int cSrc = ((lane & 7) ^ l8) * 8;
    const short* aSrc = Pp + (size_t)(qloc + wave * 8 + l8) * SS + cSrc;
    const short* bSrc = Vt + (size_t)(wave * 8 + l8) * SS + cSrc;
    const int stDst = wave * 8 * 64;
    const int sw = r & 7;
    const int qw = wave * 32;

    bf16x8 bOnes;
    #pragma unroll
    for (int j = 0; j < 8; ++j) bOnes[j] = (r == 0) ? (short)0x3F80 : (short)0;

    f32x4 acc[2][5] = {};

    G1_STAGE(As0, Bs0, kb)
    __syncthreads();
    for (int s = 0; s < 8; s += 2) {
        G1_STAGE(As1, Bs1, kb + (s + 1) * 64)
        G1_COMPUTE(As0, Bs0)
        __syncthreads();
        if (s + 2 < 8) G1_STAGE(As0, Bs0, kb + (s + 2) * 64)
        G1_COMPUTE(As1, Bs1)
        __syncthreads();
    }

    float* tp = Tpart + (size_t)kch * MTOT * D2;
    const int r4 = half * 4;
    #pragma unroll
    for (int mi = 0; mi < 2; ++mi)
        #pragma unroll
        for (int ni = 0; ni < 5; ++ni)
            #pragma unroll
            for (int ri = 0; ri < 4; ++ri)
                tp[(size_t)(mtile * 128 + qw + mi * 16 + r4 + ri) * D2 + ni * 16 + r] = acc[mi][ni][ri];
}

// ---------------------------------------------------------------------------
// K5: reduce split-K partials -> Tcat [8192][160] bf16 = [hi(80) | lo(80)].
// grid 640, block 256 (4 cols/thread).
// ---------------------------------------------------------------------------
__global__ __launch_bounds__(256) void k_reduce(
    const float* __restrict__ Tpart, short* __restrict__ Tcat)
{
    int g = blockIdx.x * 256 + threadIdx.x;      // 0..163839
    int q = g / 20;
    int c = (g % 20) * 4;
    f32x4 s = {};
    #pragma unroll
    for (int kc = 0; kc < 4; ++kc)
        s += *(const f32x4*)(Tpart + ((size_t)kc * MTOT + q) * D2 + c);
    bf16x4 hi, lo;
    #pragma unroll
    for (int j = 0; j < 4; ++j) {
        short h = f2bf(s[j]);
        hi[j] = h;
        lo[j] = f2bf(s[j] - bf2f(h));
    }
    *(bf16x4*)(Tcat + (size_t)q * K2 + c) = hi;
    *(bf16x4*)(Tcat + (size_t)q * K2 + D2 + c) = lo;
}

// ---------------------------------------------------------------------------
// K6: GEMM2 — out[q][v] = Tcat[q][:] @ Wcat[v][:] (K=160). Direct-frag
// (both operands L2/L3-hot and contiguous along k); 128x128 tile, 4 waves;
// XCD-chunked swizzle. Write-bound. grid 512 flat, block 256.
// ---------------------------------------------------------------------------
__global__ __launch_bounds__(256) void k_gemm2(
    const short* __restrict__ Tcat, const short* __restrict__ Wcat,
    float* __restrict__ out)
{
    const int tid = threadIdx.x, wave = tid >> 6, lane = tid & 63;
    const int r = lane & 15, half = lane >> 4;
    const int wm = wave >> 1, wn = wave & 1;
    const int bid = blockIdx.x;
    const int w = (bid & 7) * 64 + (bid >> 3);
    const int qB = (w >> 3) * 128;               // 0..8064
    const int vB = (w & 7) * 128;

    f32x4 acc[4][4] = {};
    #pragma unroll
    for (int ks = 0; ks < 5; ++ks) {
        bf16x8 a[4], b[4];
        #pragma unroll
        for (int i = 0; i < 4; ++i) {
            a[i] = *(const bf16x8*)(Tcat + (size_t)(qB + wm * 64 + i * 16 + r) * K2 + ks * 32 + half * 8);
            b[i] = *(const bf16x8*)(Wcat + (size_t)(vB + wn * 64 + i * 16 + r) * K2 + ks * 32 + half * 8);
        }
        #pragma unroll
        for (int mi = 0; mi < 4; ++mi)
            #pragma unroll
            for (int ni = 0; ni < 4; ++ni)
                acc[mi][ni] = mfma16(a[mi], b[ni], acc[mi][ni]);
    }

    const int r4 = half * 4;
    #pragma unroll
    for (int mi = 0; mi < 4; ++mi)
        #pragma unroll
        for (int ni = 0; ni < 4; ++ni)
            #pragma unroll
            for (int ri = 0; ri < 4; ++ri)
                out[(size_t)(qB + wm * 64 + mi * 16 + r4 + ri) * EE + vB + wn * 64 + ni * 16 + r] = acc[mi][ni][ri];
}

// ---------------------------------------------------------------------------
extern "C" void kernel_launch(void* const* d_in, const int* in_sizes, int n_in,
                              void* d_out, int out_size, void* d_ws, size_t ws_size,
                              hipStream_t stream) {
    (void)in_sizes; (void)n_in; (void)out_size; (void)ws_size;
    const float* x   = (const float*)d_in[0];
    const float* y   = (const float*)d_in[1];
    const float* Wq  = (const float*)d_in[2];
    const float* bq  = (const float*)d_in[3];
    const float* Wk  = (const float*)d_in[4];
    const float* bk  = (const float*)d_in[5];
    const float* WvR = (const float*)d_in[6];
    const float* bvR = (const float*)d_in[7];
    const float* WvL = (const float*)d_in[8];
    const float* bvL = (const float*)d_in[9];
    float* out = (float*)d_out;

    // workspace layout (shorts unless noted):
    short* Qb   = (short*)d_ws;                       // 524288
    short* Kb   = Qb   + (size_t)MTOT * DD;           // 524288
    short* VRb  = Kb   + (size_t)MTOT * DD;           // 524288
    short* VRbT = VRb  + (size_t)MTOT * DD;           // 524288
    short* Pb   = VRbT + (size_t)MTOT * DD;           // 16777216
    short* Tcat = Pb   + (size_t)NB * SS * SS;        // 1310720
    short* Wqb  = Tcat + (size_t)MTOT * K2;           // 65536
    short* Wkb  = Wqb  + (size_t)DD * EE;
    short* Wvb  = Wkb  + (size_t)DD * EE;
    short* Wcat = Wvb  + (size_t)DD * EE;             // 163840
    float* Tpart = (float*)(Wcat + (size_t)EE * K2);  // 4*8192*80 f32 (10.5MB)

    k_prep<<<dim3(96), 256, 0, stream>>>(Wq, Wk, WvR, Wqb, Wkb, Wvb);
    k_wprep<<<dim3(80), 256, 0, stream>>>(WvL, bvL, Wcat);
    k_proj<<<dim3(MTOT / 16, 2), 256, 0, stream>>>(x, y, Wqb, Wkb, Wvb, bq, bk, bvR, Qb, Kb, VRb);
    k_tr<<<dim3(MTOT / 64), 256, 0, stream>>>(VRb, VRbT);
    k_softmax<<<dim3(SS / 16, NB), 512, 0, stream>>>(Qb, Kb, Pb);
    k_gemm1<<<dim3(256), 256, 0, stream>>>(Pb, VRbT, Tpart);
    k_reduce<<<dim3(640), 256, 0, stream>>>(Tpart, Tcat);
    k_gemm2<<<dim3(512), 256, 0, stream>>>(Tcat, Wcat, out);
}